// Round 2
// baseline (735.598 us; speedup 1.0000x reference)
//
#include <hip/hip_runtime.h>
#include <hip/hip_bf16.h>

typedef __bf16 bf16x8 __attribute__((ext_vector_type(8)));
typedef float f32x4 __attribute__((ext_vector_type(4)));

#define MROWS 8192
#define DD 1024
#define DN 4096

__device__ __forceinline__ void load_lds16(const void* g, void* l) {
  __builtin_amdgcn_global_load_lds((const __attribute__((address_space(1))) void*)g,
                                   (__attribute__((address_space(3))) void*)l, 16, 0, 0);
}

// C[M,N] = A[M,K] @ B[N,K]^T ; A,B bf16 row-major K-contiguous.
// Tile 128x128, BK=64, 256 threads (4 waves, 2x2), 16x16x32 bf16 MFMA, acc 4x4.
// LDS: A [128][64]bf16 at 0 (16KB), B at 16384. Chunk-XOR swizzle (chunk ^= row&7)
// applied on the *global source* address (LDS write stays linear, required by
// global_load_lds); inverse XOR applied on the ds_read side.
// EPI: 0 = f32 store (pred), 1 = relu->bf16 (h1), 2 = relu->bf16 + sum->vsum (h2),
//      3 = final: out = x + sigmoid(v + b) * pred  (f32)
template<int EPI>
__global__ void __launch_bounds__(256)
gemm_bt(const __hip_bfloat16* __restrict__ A, const __hip_bfloat16* __restrict__ B,
        void* __restrict__ Cv, int M, int N, int K,
        float* __restrict__ vsum, const float* __restrict__ Xf,
        const float* __restrict__ Pred, const float* __restrict__ Bgate)
{
  __shared__ __align__(16) char smem[32768];
  const int tid  = threadIdx.x;
  const int lane = tid & 63;
  const int wave = tid >> 6;

  const int nbn = N >> 7;
  const int bm = (blockIdx.x / nbn) << 7;
  const int bn = (blockIdx.x % nbn) << 7;

  const int wm = (wave >> 1) << 6;
  const int wn = (wave & 1) << 6;

  const f32x4 zero = {0.f, 0.f, 0.f, 0.f};
  f32x4 acc[4][4];
#pragma unroll
  for (int i = 0; i < 4; ++i)
#pragma unroll
    for (int j = 0; j < 4; ++j)
      acc[i][j] = zero;

  // staging: thread t -> row t/8 (+32 per issue), 16B chunk t%8, source chunk
  // pre-swizzled by row&7 (invariant across issues since 32 % 8 == 0)
  const int srow = tid >> 3;
  const int schk = (tid & 7) ^ (srow & 7);
  const __hip_bfloat16* Ag = A + (size_t)(bm + srow) * K + (schk << 3);
  const __hip_bfloat16* Bg = B + (size_t)(bn + srow) * K + (schk << 3);
  char* ldsA = smem + (wave << 10);
  char* ldsB = smem + 16384 + (wave << 10);

  // fragment read bases: row = w{m,n} + i*16 + (lane&15); k-chunk = (lane>>4)+4*ks
  const int aoff0 = (wm + (lane & 15)) << 7;
  const int boff0 = 16384 + ((wn + (lane & 15)) << 7);
  const int kc = lane >> 4;
  const int sw = lane & 7; // == (row & 7) since wm/wn + i*16 is 0 mod 8

  for (int k0 = 0; k0 < K; k0 += 64) {
#pragma unroll
    for (int i = 0; i < 4; ++i)
      load_lds16(Ag + (size_t)(i << 5) * K + k0, ldsA + (i << 12));
#pragma unroll
    for (int i = 0; i < 4; ++i)
      load_lds16(Bg + (size_t)(i << 5) * K + k0, ldsB + (i << 12));
    __syncthreads();
#pragma unroll
    for (int ks = 0; ks < 2; ++ks) {
      const int cb = ((kc + (ks << 2)) ^ sw) << 4;
      bf16x8 af[4], bfr[4];
#pragma unroll
      for (int i = 0; i < 4; ++i)
        af[i] = *reinterpret_cast<const bf16x8*>(smem + aoff0 + (i << 11) + cb);
#pragma unroll
      for (int j = 0; j < 4; ++j)
        bfr[j] = *reinterpret_cast<const bf16x8*>(smem + boff0 + (j << 11) + cb);
#pragma unroll
      for (int i = 0; i < 4; ++i)
#pragma unroll
        for (int j = 0; j < 4; ++j)
          acc[i][j] = __builtin_amdgcn_mfma_f32_16x16x32_bf16(af[i], bfr[j], acc[i][j], 0, 0, 0);
    }
    __syncthreads();
  }

  float* Cf = (float*)Cv;
  __hip_bfloat16* Cb = (__hip_bfloat16*)Cv;

  // epilogue: C/D layout col = lane&15, row = (lane>>4)*4 + q
  const int r0 = bm + wm + ((lane >> 4) << 2);
  const int c0 = bn + wn + (lane & 15);
  float lsum = 0.f;
#pragma unroll
  for (int i = 0; i < 4; ++i) {
#pragma unroll
    for (int j = 0; j < 4; ++j) {
#pragma unroll
      for (int q = 0; q < 4; ++q) {
        const int r = r0 + (i << 4) + q;
        const int c = c0 + (j << 4);
        const size_t idx = (size_t)r * N + c;
        float v = acc[i][j][q];
        if constexpr (EPI == 0) {
          Cf[idx] = v;
        } else if constexpr (EPI == 1) {
          Cb[idx] = __float2bfloat16(fmaxf(v, 0.f));
        } else if constexpr (EPI == 2) {
          v = fmaxf(v, 0.f);
          Cb[idx] = __float2bfloat16(v);
          lsum += v;
        } else {
          const float g = 1.f / (1.f + __expf(-(v + Bgate[c])));
          Cf[idx] = Xf[idx] + g * Pred[idx];
        }
      }
    }
  }
  if constexpr (EPI == 2) {
#pragma unroll
    for (int off = 32; off > 0; off >>= 1)
      lsum += __shfl_down(lsum, off);
    if (lane == 0) atomicAdd(vsum, lsum);
  }
}

// Exact kwta per row on bf16 input (values >= 0 post-relu so float-bit order ==
// numeric order): 4-pass radix select, thresh = k-th largest incl. duplicates;
// keep v >= thresh (matches jnp.top_k + where semantics on the rounded values).
// MODE 0: OUT = kept/norm (sparse).  MODE 1: OUT = valid ? kept/norm : OUT.
template<int MODE>
__global__ void __launch_bounds__(256)
kwta_kernel(const __hip_bfloat16* __restrict__ H, __hip_bfloat16* __restrict__ OUT,
            const float* __restrict__ vsumPtr, const int* __restrict__ kptr)
{
  __shared__ __align__(16) float vals[4096];
  __shared__ unsigned hist[256];
  __shared__ unsigned sfx[256];
  __shared__ unsigned sh_pr, sh_rem;
  __shared__ float wred[4];

  const int tid = threadIdx.x;
  const int row = blockIdx.x;
  const uint4* h8 = (const uint4*)(H + (size_t)row * 4096);

#pragma unroll
  for (int i = 0; i < 2; ++i) {
    const int u4 = tid + (i << 8);          // uint4 index, 8 bf16 each
    const uint4 u = h8[u4];
    const int base = u4 << 3;
    vals[base + 0] = __uint_as_float(u.x << 16);
    vals[base + 1] = __uint_as_float(u.x & 0xffff0000u);
    vals[base + 2] = __uint_as_float(u.y << 16);
    vals[base + 3] = __uint_as_float(u.y & 0xffff0000u);
    vals[base + 4] = __uint_as_float(u.z << 16);
    vals[base + 5] = __uint_as_float(u.z & 0xffff0000u);
    vals[base + 6] = __uint_as_float(u.w << 16);
    vals[base + 7] = __uint_as_float(u.w & 0xffff0000u);
  }
  __syncthreads();

  unsigned prefix = 0;
  unsigned remaining = (unsigned)(*kptr);

  for (int shift = 24; shift >= 0; shift -= 8) {
    hist[tid] = 0;
    __syncthreads();
#pragma unroll
    for (int i = 0; i < 16; ++i) {
      const unsigned u = __float_as_uint(vals[tid + (i << 8)]);
      const bool ok = (shift == 24) ? true : ((u >> (shift + 8)) == prefix);
      if (ok) atomicAdd(&hist[(u >> shift) & 255], 1u);
    }
    __syncthreads();
    const unsigned own = hist[tid];
    sfx[tid] = own;
    __syncthreads();
#pragma unroll
    for (int off = 1; off < 256; off <<= 1) {
      const unsigned t = (tid + off < 256) ? sfx[tid + off] : 0u;
      __syncthreads();
      sfx[tid] += t;
      __syncthreads();
    }
    const unsigned ge = sfx[tid];      // count in bins >= tid
    const unsigned gt = ge - own;      // count in bins >  tid
    if (gt < remaining && remaining <= ge) {
      sh_pr = (prefix << 8) | (unsigned)tid;
      sh_rem = remaining - gt;
    }
    __syncthreads();
    prefix = sh_pr;
    remaining = sh_rem;
    __syncthreads();
  }

  const float thresh = __uint_as_float(prefix);

  float ss = 0.f;
#pragma unroll
  for (int i = 0; i < 16; ++i) {
    const float v = vals[tid + (i << 8)];
    if (v >= thresh) ss += v * v;
  }
#pragma unroll
  for (int off = 32; off > 0; off >>= 1) ss += __shfl_down(ss, off);
  if ((tid & 63) == 0) wred[tid >> 6] = ss;
  __syncthreads();
  const float total = wred[0] + wred[1] + wred[2] + wred[3];
  const float inv = 1.f / fmaxf(sqrtf(total), 1e-10f);

  if (MODE == 1) {
    if (!(*vsumPtr >= 1e-10f)) return; // successor = sparse (already in OUT)
  }

  uint4* o8 = (uint4*)(OUT + (size_t)row * 4096);
#pragma unroll
  for (int i = 0; i < 2; ++i) {
    const int u4 = tid + (i << 8);
    const int base = u4 << 3;
    union { __hip_bfloat16 hh[8]; uint4 u; } pk;
#pragma unroll
    for (int e = 0; e < 8; ++e) {
      const float v = vals[base + e];
      pk.hh[e] = __float2bfloat16((v >= thresh) ? v * inv : 0.f);
    }
    o8[u4] = pk.u;
  }
}

__global__ void __launch_bounds__(256)
cvt_bf16(const float* __restrict__ in, __hip_bfloat16* __restrict__ out, int n8)
{
  const int i = blockIdx.x * 256 + threadIdx.x;
  if (i >= n8) return;
  const float4 a = ((const float4*)in)[2 * i];
  const float4 b = ((const float4*)in)[2 * i + 1];
  union { __hip_bfloat16 h[8]; uint4 u; } pk;
  pk.h[0] = __float2bfloat16(a.x); pk.h[1] = __float2bfloat16(a.y);
  pk.h[2] = __float2bfloat16(a.z); pk.h[3] = __float2bfloat16(a.w);
  pk.h[4] = __float2bfloat16(b.x); pk.h[5] = __float2bfloat16(b.y);
  pk.h[6] = __float2bfloat16(b.z); pk.h[7] = __float2bfloat16(b.w);
  ((uint4*)out)[i] = pk.u;
}

// Diagnostic: if ws_size is insufficient, encode it (in MB, negated) in d_out[0]
// so the reported absmax tells us the real budget.
__global__ void diag_kernel(float* out, float mb)
{
  if (threadIdx.x == 0 && blockIdx.x == 0) out[0] = -mb;
}

extern "C" void kernel_launch(void* const* d_in, const int* in_sizes, int n_in,
                              void* d_out, int out_size, void* d_ws, size_t ws_size,
                              hipStream_t stream)
{
  const float* x     = (const float*)d_in[0]; // (8192,1024)
  const float* Wdown = (const float*)d_in[1]; // (4096,1024)
  const float* Wup   = (const float*)d_in[2]; // (1024,4096)
  const float* Wgate = (const float*)d_in[3]; // (1024,1024)
  const float* bgate = (const float*)d_in[4]; // (1024,)
  const float* Wca3  = (const float*)d_in[5]; // (4096,4096)
  const int*   kptr  = (const int*)d_in[6];

  // workspace layout (bytes)
  const size_t OFF_XBF  = 0;          // 16 MB bf16 x
  const size_t OFF_WDBF = 16777216;   //  8 MB bf16 W_down
  const size_t OFF_WUBF = 25165824;   //  8 MB bf16 W_up
  const size_t OFF_WGBF = 33554432;   //  2 MB bf16 W_gate
  const size_t OFF_WCBF = 35651584;   // 32 MB bf16 W_ca3
  const size_t OFF_SP   = 69206016;   // 64 MB bf16 sparse/successor
  const size_t OFF_H    = 136314880;  // 64 MB bf16 h1/h2; pred (32 MB f32) aliases
  const size_t OFF_VSUM = 203423744;  // 4 B
  const size_t NEED     = 203423748;

  if (ws_size < NEED) {
    diag_kernel<<<1, 64, 0, stream>>>((float*)d_out, (float)(ws_size >> 20));
    return;
  }

  char* ws = (char*)d_ws;
  __hip_bfloat16* xbf  = (__hip_bfloat16*)(ws + OFF_XBF);
  __hip_bfloat16* wdbf = (__hip_bfloat16*)(ws + OFF_WDBF);
  __hip_bfloat16* wubf = (__hip_bfloat16*)(ws + OFF_WUBF);
  __hip_bfloat16* wgbf = (__hip_bfloat16*)(ws + OFF_WGBF);
  __hip_bfloat16* wcbf = (__hip_bfloat16*)(ws + OFF_WCBF);
  __hip_bfloat16* sp   = (__hip_bfloat16*)(ws + OFF_SP);
  __hip_bfloat16* h    = (__hip_bfloat16*)(ws + OFF_H);
  float*          pred = (float*)         (ws + OFF_H);   // aliases h (dead by then)
  float*          vsum = (float*)         (ws + OFF_VSUM);

  hipMemsetAsync(vsum, 0, sizeof(float), stream);

  // f32 -> bf16 conversions
  cvt_bf16<<<(MROWS * DD / 8 + 255) / 256, 256, 0, stream>>>(x, xbf, MROWS * DD / 8);
  cvt_bf16<<<(DN * DD / 8 + 255) / 256, 256, 0, stream>>>(Wdown, wdbf, DN * DD / 8);
  cvt_bf16<<<(DN * DN / 8 + 255) / 256, 256, 0, stream>>>(Wca3, wcbf, DN * DN / 8);
  cvt_bf16<<<(DD * DN / 8 + 255) / 256, 256, 0, stream>>>(Wup, wubf, DD * DN / 8);
  cvt_bf16<<<(DD * DD / 8 + 255) / 256, 256, 0, stream>>>(Wgate, wgbf, DD * DD / 8);

  // h1 = relu(x @ W_down.T)  -> bf16
  gemm_bt<1><<<(MROWS >> 7) * (DN >> 7), 256, 0, stream>>>(
      xbf, wdbf, h, MROWS, DN, DD, nullptr, nullptr, nullptr, nullptr);
  // sparse = kwta(h1)/norm
  kwta_kernel<0><<<MROWS, 256, 0, stream>>>(h, sp, nullptr, kptr);
  // h2 = relu(sparse @ W_ca3.T) -> bf16, accumulate global sum -> vsum
  gemm_bt<2><<<(MROWS >> 7) * (DN >> 7), 256, 0, stream>>>(
      sp, wcbf, h, MROWS, DN, DN, vsum, nullptr, nullptr, nullptr);
  // successor = valid ? kwta(h2)/norm : sparse (in-place in sp)
  kwta_kernel<1><<<MROWS, 256, 0, stream>>>(h, sp, vsum, kptr);
  // pred = successor @ W_up.T  (f32, overwrites h region)
  gemm_bt<0><<<(MROWS >> 7) * (DD >> 7), 256, 0, stream>>>(
      sp, wubf, pred, MROWS, DD, DN, nullptr, nullptr, nullptr, nullptr);
  // out = x + sigmoid(x @ W_gate.T + b_gate) * pred
  gemm_bt<3><<<(MROWS >> 7) * (DD >> 7), 256, 0, stream>>>(
      xbf, wgbf, (float*)d_out, MROWS, DD, DD, nullptr, x, pred, bgate);
}

// Round 3
// 678.595 us; speedup vs baseline: 1.0840x; 1.0840x over previous
//
#include <hip/hip_runtime.h>
#include <hip/hip_bf16.h>

typedef __bf16 bf16x8 __attribute__((ext_vector_type(8)));
typedef float f32x4 __attribute__((ext_vector_type(4)));

#define MROWS 8192
#define DD 1024
#define DN 4096

__device__ __forceinline__ void load_lds16(const void* g, void* l) {
  __builtin_amdgcn_global_load_lds((const __attribute__((address_space(1))) void*)g,
                                   (__attribute__((address_space(3))) void*)l, 16, 0, 0);
}

// ============================================================================
// 256x256 8-phase GEMM (m201-style): C[M,N] = A[M,K] @ B[N,K]^T, A,B bf16.
// 512 threads = 8 waves (2M x 4N); per-wave output 128x64 (8x4 frags 16x16).
// LDS ring (dynamic, 128 KiB): A-slots[parity][khalf] 4 x 16KB at 0,
// B-slots at 65536. Slot = 256 rows x 32 K bf16, row-major 64B rows, 16B
// chunks XOR-swizzled (chunk ^= (row>>1)&3) via pre-swizzled global source.
// Per iter (2 K-tiles, 8 phases): phase (tilepar P, khalf KH, mhalf MH):
//   ds_read 4 A-frags (+4 B-frags if MH==0) ; stage 1 half-tile (2 gload_lds);
//   [vmcnt(4) at phases 4,8] ; s_barrier ; lgkmcnt(0)+sched_barrier ;
//   setprio(1) ; 16 MFMA ; setprio(0) ; s_barrier.
// Counted vmcnt(4) = 2 half-tiles in flight; never drains to 0 in the loop.
// EPI: 1 = relu->bf16, 2 = relu->bf16 + block sum -> atomicAdd(vsum)
// ============================================================================
template<int EPI>
__global__ void __launch_bounds__(512, 1)
gemm_bt8(const __hip_bfloat16* __restrict__ A, const __hip_bfloat16* __restrict__ B,
         __hip_bfloat16* __restrict__ Cb, int M, int N, int K,
         float* __restrict__ vsum)
{
  extern __shared__ __align__(16) char smem[];
  const int tid  = threadIdx.x;
  const int lane = tid & 63;
  const int wave = tid >> 6;
  const int wm = wave >> 2;   // 0..1
  const int wn = wave & 3;    // 0..3

  // XCD-aware swizzle (grid % 8 == 0 for all our launches)
  const int nwg = gridDim.x;
  const int bid = ((int)blockIdx.x % 8) * (nwg >> 3) + ((int)blockIdx.x >> 3);

  const int nbn = N >> 8;
  const int bm = (bid / nbn) << 8;
  const int bn = (bid % nbn) << 8;

  const int NT = K >> 6;  // K-tiles (power of two: 16 or 64)

  f32x4 acc[8][4];
  const f32x4 zero = {0.f, 0.f, 0.f, 0.f};
#pragma unroll
  for (int i = 0; i < 8; ++i)
#pragma unroll
    for (int j = 0; j < 4; ++j)
      acc[i][j] = zero;

  // ---- staging constants: thread covers row tid>>2 (+128 on 2nd issue),
  // LDS chunk tid&3; source chunk pre-swizzled by (row>>1)&3 = (tid>>3)&3.
  const int cs8 = (((tid & 3) ^ ((tid >> 3) & 3)) << 3); // k-elem offset in khalf
  const __hip_bfloat16* Ag = A + (size_t)(bm + (tid >> 2)) * K + cs8;
  const __hip_bfloat16* Bg = B + (size_t)(bn + (tid >> 2)) * K + cs8;

  // ---- fragment-read constants: row = base + rl, k-chunk kc, swizzle (rl>>1)&3
  const int rl = lane & 15;
  const int kc = lane >> 4;
  const int chunk_off = ((kc ^ ((rl >> 1) & 3)) << 4);
  const int aoff = ((wm << 7) + rl) * 64 + chunk_off;  // within A slot
  const int boff = ((wn << 6) + rl) * 64 + chunk_off;  // within B slot

#define STAGE_A(S, KH) do { \
    const int kt_ = (((S) & (NT - 1)) << 6) + ((KH) << 5); \
    char* dst_ = smem + (((((S) & 1) << 1) | (KH)) << 14) + (tid << 4); \
    load_lds16(Ag + kt_, dst_); \
    load_lds16(Ag + (size_t)128 * K + kt_, dst_ + 8192); \
  } while (0)

#define STAGE_B(S, KH) do { \
    const int kt_ = (((S) & (NT - 1)) << 6) + ((KH) << 5); \
    char* dst_ = smem + 65536 + (((((S) & 1) << 1) | (KH)) << 14) + (tid << 4); \
    load_lds16(Bg + kt_, dst_); \
    load_lds16(Bg + (size_t)128 * K + kt_, dst_ + 8192); \
  } while (0)

  bf16x8 af0, af1, af2, af3, bf0, bf1, bf2, bf3;

#define DS_A(P, KH, MH) do { \
    const char* ab_ = smem + ((((P) << 1) | (KH)) << 14) + aoff + (MH) * 4096; \
    af0 = *(const bf16x8*)(ab_); \
    af1 = *(const bf16x8*)(ab_ + 1024); \
    af2 = *(const bf16x8*)(ab_ + 2048); \
    af3 = *(const bf16x8*)(ab_ + 3072); \
  } while (0)

#define DS_B(P, KH) do { \
    const char* bb_ = smem + 65536 + ((((P) << 1) | (KH)) << 14) + boff; \
    bf0 = *(const bf16x8*)(bb_); \
    bf1 = *(const bf16x8*)(bb_ + 1024); \
    bf2 = *(const bf16x8*)(bb_ + 2048); \
    bf3 = *(const bf16x8*)(bb_ + 3072); \
  } while (0)

#define MFMA_ROW(MI, AF) \
    acc[MI][0] = __builtin_amdgcn_mfma_f32_16x16x32_bf16(AF, bf0, acc[MI][0], 0, 0, 0); \
    acc[MI][1] = __builtin_amdgcn_mfma_f32_16x16x32_bf16(AF, bf1, acc[MI][1], 0, 0, 0); \
    acc[MI][2] = __builtin_amdgcn_mfma_f32_16x16x32_bf16(AF, bf2, acc[MI][2], 0, 0, 0); \
    acc[MI][3] = __builtin_amdgcn_mfma_f32_16x16x32_bf16(AF, bf3, acc[MI][3], 0, 0, 0);

#define PH(P, KH, MH, STG, VM) do { \
    DS_A(P, KH, MH); \
    if ((MH) == 0) { DS_B(P, KH); } \
    STG; \
    if (VM) { asm volatile("s_waitcnt vmcnt(4)" ::: "memory"); } \
    asm volatile("s_barrier" ::: "memory"); \
    asm volatile("s_waitcnt lgkmcnt(0)" ::: "memory"); \
    __builtin_amdgcn_sched_barrier(0); \
    __builtin_amdgcn_s_setprio(1); \
    MFMA_ROW((MH) * 4 + 0, af0) \
    MFMA_ROW((MH) * 4 + 1, af1) \
    MFMA_ROW((MH) * 4 + 2, af2) \
    MFMA_ROW((MH) * 4 + 3, af3) \
    __builtin_amdgcn_s_setprio(0); \
    asm volatile("s_barrier" ::: "memory"); \
  } while (0)

  // ---- prologue: tile0 fully + tile1 khalf0; all-but-newest-2-halftiles wait
  STAGE_A(0, 0); STAGE_B(0, 0);
  STAGE_A(0, 1); STAGE_B(0, 1);
  STAGE_A(1, 0); STAGE_B(1, 0);
  asm volatile("s_waitcnt vmcnt(4)" ::: "memory");
  asm volatile("s_barrier" ::: "memory");

  // ---- main loop: 2 K-tiles per iter; tail stages wrap (never read, WAR-safe)
  for (int t = 0; t < NT; t += 2) {
    PH(0, 0, 0, STAGE_A(t + 1, 1), 0);
    PH(0, 0, 1, STAGE_B(t + 1, 1), 0);
    PH(0, 1, 0, STAGE_A(t + 2, 0), 0);
    PH(0, 1, 1, STAGE_B(t + 2, 0), 1);
    PH(1, 0, 0, STAGE_A(t + 2, 1), 0);
    PH(1, 0, 1, STAGE_B(t + 2, 1), 0);
    PH(1, 1, 0, STAGE_A(t + 3, 0), 0);
    PH(1, 1, 1, STAGE_B(t + 3, 0), 1);
  }

  // ---- epilogue: C/D frag layout col = lane&15, row = (lane>>4)*4 + q
  const int r0 = bm + (wm << 7) + (kc << 2);
  const int c0 = bn + (wn << 6) + rl;
  float lsum = 0.f;
#pragma unroll
  for (int mi = 0; mi < 8; ++mi) {
#pragma unroll
    for (int nf = 0; nf < 4; ++nf) {
#pragma unroll
      for (int q = 0; q < 4; ++q) {
        const int r = r0 + (mi << 4) + q;
        const int c = c0 + (nf << 4);
        float v = fmaxf(acc[mi][nf][q], 0.f);
        Cb[(size_t)r * N + c] = __float2bfloat16(v);
        if constexpr (EPI == 2) lsum += v;
      }
    }
  }
  if constexpr (EPI == 2) {
#pragma unroll
    for (int off = 32; off > 0; off >>= 1)
      lsum += __shfl_down(lsum, off);
    if (lane == 0) atomicAdd(vsum, lsum);
  }

#undef STAGE_A
#undef STAGE_B
#undef DS_A
#undef DS_B
#undef MFMA_ROW
#undef PH
}

// ============================================================================
// 128x128 2-barrier GEMM (m97-style) — kept for N=1024 outputs (grid density)
// EPI: 0 = f32 store (pred), 3 = final: out = x + sigmoid(v + b) * pred (f32)
// ============================================================================
template<int EPI>
__global__ void __launch_bounds__(256)
gemm_bt(const __hip_bfloat16* __restrict__ A, const __hip_bfloat16* __restrict__ B,
        float* __restrict__ Cf, int M, int N, int K,
        const float* __restrict__ Xf, const float* __restrict__ Pred,
        const float* __restrict__ Bgate)
{
  __shared__ __align__(16) char smem[32768];
  const int tid  = threadIdx.x;
  const int lane = tid & 63;
  const int wave = tid >> 6;

  const int nbn = N >> 7;
  const int bm = ((int)blockIdx.x / nbn) << 7;
  const int bn = ((int)blockIdx.x % nbn) << 7;

  const int wm = (wave >> 1) << 6;
  const int wn = (wave & 1) << 6;

  const f32x4 zero = {0.f, 0.f, 0.f, 0.f};
  f32x4 acc[4][4];
#pragma unroll
  for (int i = 0; i < 4; ++i)
#pragma unroll
    for (int j = 0; j < 4; ++j)
      acc[i][j] = zero;

  const int srow = tid >> 3;
  const int schk = (tid & 7) ^ (srow & 7);
  const __hip_bfloat16* Ag = A + (size_t)(bm + srow) * K + (schk << 3);
  const __hip_bfloat16* Bg = B + (size_t)(bn + srow) * K + (schk << 3);
  char* ldsA = smem + (wave << 10);
  char* ldsB = smem + 16384 + (wave << 10);

  const int aoff0 = (wm + (lane & 15)) << 7;
  const int boff0 = 16384 + ((wn + (lane & 15)) << 7);
  const int kc = lane >> 4;
  const int sw = lane & 7;

  for (int k0 = 0; k0 < K; k0 += 64) {
#pragma unroll
    for (int i = 0; i < 4; ++i)
      load_lds16(Ag + (size_t)(i << 5) * K + k0, ldsA + (i << 12));
#pragma unroll
    for (int i = 0; i < 4; ++i)
      load_lds16(Bg + (size_t)(i << 5) * K + k0, ldsB + (i << 12));
    __syncthreads();
#pragma unroll
    for (int ks = 0; ks < 2; ++ks) {
      const int cb = ((kc + (ks << 2)) ^ sw) << 4;
      bf16x8 af[4], bfr[4];
#pragma unroll
      for (int i = 0; i < 4; ++i)
        af[i] = *reinterpret_cast<const bf16x8*>(smem + aoff0 + (i << 11) + cb);
#pragma unroll
      for (int j = 0; j < 4; ++j)
        bfr[j] = *reinterpret_cast<const bf16x8*>(smem + boff0 + (j << 11) + cb);
#pragma unroll
      for (int i = 0; i < 4; ++i)
#pragma unroll
        for (int j = 0; j < 4; ++j)
          acc[i][j] = __builtin_amdgcn_mfma_f32_16x16x32_bf16(af[i], bfr[j], acc[i][j], 0, 0, 0);
    }
    __syncthreads();
  }

  const int r0 = bm + wm + ((lane >> 4) << 2);
  const int c0 = bn + wn + (lane & 15);
#pragma unroll
  for (int i = 0; i < 4; ++i) {
#pragma unroll
    for (int j = 0; j < 4; ++j) {
#pragma unroll
      for (int q = 0; q < 4; ++q) {
        const int r = r0 + (i << 4) + q;
        const int c = c0 + (j << 4);
        const size_t idx = (size_t)r * N + c;
        float v = acc[i][j][q];
        if constexpr (EPI == 0) {
          Cf[idx] = v;
        } else {
          const float g = 1.f / (1.f + __expf(-(v + Bgate[c])));
          Cf[idx] = Xf[idx] + g * Pred[idx];
        }
      }
    }
  }
}

// Exact kwta per row on bf16 input (values >= 0 post-relu): 4-pass radix
// select; thresh = k-th largest incl. dups; keep v >= thresh.
// MODE 0: OUT = kept/norm. MODE 1: OUT = valid ? kept/norm : OUT (unchanged).
template<int MODE>
__global__ void __launch_bounds__(256)
kwta_kernel(const __hip_bfloat16* __restrict__ H, __hip_bfloat16* __restrict__ OUT,
            const float* __restrict__ vsumPtr, const int* __restrict__ kptr)
{
  __shared__ __align__(16) float vals[4096];
  __shared__ unsigned hist[256];
  __shared__ unsigned sfx[256];
  __shared__ unsigned sh_pr, sh_rem;
  __shared__ float wred[4];

  const int tid = threadIdx.x;
  const int row = blockIdx.x;
  const uint4* h8 = (const uint4*)(H + (size_t)row * 4096);

#pragma unroll
  for (int i = 0; i < 2; ++i) {
    const int u4 = tid + (i << 8);
    const uint4 u = h8[u4];
    const int base = u4 << 3;
    vals[base + 0] = __uint_as_float(u.x << 16);
    vals[base + 1] = __uint_as_float(u.x & 0xffff0000u);
    vals[base + 2] = __uint_as_float(u.y << 16);
    vals[base + 3] = __uint_as_float(u.y & 0xffff0000u);
    vals[base + 4] = __uint_as_float(u.z << 16);
    vals[base + 5] = __uint_as_float(u.z & 0xffff0000u);
    vals[base + 6] = __uint_as_float(u.w << 16);
    vals[base + 7] = __uint_as_float(u.w & 0xffff0000u);
  }
  __syncthreads();

  unsigned prefix = 0;
  unsigned remaining = (unsigned)(*kptr);

  for (int shift = 24; shift >= 0; shift -= 8) {
    hist[tid] = 0;
    __syncthreads();
#pragma unroll
    for (int i = 0; i < 16; ++i) {
      const unsigned u = __float_as_uint(vals[tid + (i << 8)]);
      const bool ok = (shift == 24) ? true : ((u >> (shift + 8)) == prefix);
      if (ok) atomicAdd(&hist[(u >> shift) & 255], 1u);
    }
    __syncthreads();
    const unsigned own = hist[tid];
    sfx[tid] = own;
    __syncthreads();
#pragma unroll
    for (int off = 1; off < 256; off <<= 1) {
      const unsigned t = (tid + off < 256) ? sfx[tid + off] : 0u;
      __syncthreads();
      sfx[tid] += t;
      __syncthreads();
    }
    const unsigned ge = sfx[tid];
    const unsigned gt = ge - own;
    if (gt < remaining && remaining <= ge) {
      sh_pr = (prefix << 8) | (unsigned)tid;
      sh_rem = remaining - gt;
    }
    __syncthreads();
    prefix = sh_pr;
    remaining = sh_rem;
    __syncthreads();
  }

  const float thresh = __uint_as_float(prefix);

  float ss = 0.f;
#pragma unroll
  for (int i = 0; i < 16; ++i) {
    const float v = vals[tid + (i << 8)];
    if (v >= thresh) ss += v * v;
  }
#pragma unroll
  for (int off = 32; off > 0; off >>= 1) ss += __shfl_down(ss, off);
  if ((tid & 63) == 0) wred[tid >> 6] = ss;
  __syncthreads();
  const float total = wred[0] + wred[1] + wred[2] + wred[3];
  const float inv = 1.f / fmaxf(sqrtf(total), 1e-10f);

  if (MODE == 1) {
    if (!(*vsumPtr >= 1e-10f)) return;
  }

  uint4* o8 = (uint4*)(OUT + (size_t)row * 4096);
#pragma unroll
  for (int i = 0; i < 2; ++i) {
    const int u4 = tid + (i << 8);
    const int base = u4 << 3;
    union { __hip_bfloat16 hh[8]; uint4 u; } pk;
#pragma unroll
    for (int e = 0; e < 8; ++e) {
      const float v = vals[base + e];
      pk.hh[e] = __float2bfloat16((v >= thresh) ? v * inv : 0.f);
    }
    o8[u4] = pk.u;
  }
}

__global__ void __launch_bounds__(256)
cvt_bf16(const float* __restrict__ in, __hip_bfloat16* __restrict__ out, int n8)
{
  const int i = blockIdx.x * 256 + threadIdx.x;
  if (i >= n8) return;
  const float4 a = ((const float4*)in)[2 * i];
  const float4 b = ((const float4*)in)[2 * i + 1];
  union { __hip_bfloat16 h[8]; uint4 u; } pk;
  pk.h[0] = __float2bfloat16(a.x); pk.h[1] = __float2bfloat16(a.y);
  pk.h[2] = __float2bfloat16(a.z); pk.h[3] = __float2bfloat16(a.w);
  pk.h[4] = __float2bfloat16(b.x); pk.h[5] = __float2bfloat16(b.y);
  pk.h[6] = __float2bfloat16(b.z); pk.h[7] = __float2bfloat16(b.w);
  ((uint4*)out)[i] = pk.u;
}

__global__ void diag_kernel(float* out, float mb)
{
  if (threadIdx.x == 0 && blockIdx.x == 0) out[0] = -mb;
}

extern "C" void kernel_launch(void* const* d_in, const int* in_sizes, int n_in,
                              void* d_out, int out_size, void* d_ws, size_t ws_size,
                              hipStream_t stream)
{
  const float* x     = (const float*)d_in[0]; // (8192,1024)
  const float* Wdown = (const float*)d_in[1]; // (4096,1024)
  const float* Wup   = (const float*)d_in[2]; // (1024,4096)
  const float* Wgate = (const float*)d_in[3]; // (1024,1024)
  const float* bgate = (const float*)d_in[4]; // (1024,)
  const float* Wca3  = (const float*)d_in[5]; // (4096,4096)
  const int*   kptr  = (const int*)d_in[6];

  const size_t OFF_XBF  = 0;          // 16 MB bf16 x
  const size_t OFF_WDBF = 16777216;   //  8 MB bf16 W_down
  const size_t OFF_WUBF = 25165824;   //  8 MB bf16 W_up
  const size_t OFF_WGBF = 33554432;   //  2 MB bf16 W_gate
  const size_t OFF_WCBF = 35651584;   // 32 MB bf16 W_ca3
  const size_t OFF_SP   = 69206016;   // 64 MB bf16 sparse/successor
  const size_t OFF_H    = 136314880;  // 64 MB bf16 h1/h2; pred (32 MB f32) aliases
  const size_t OFF_VSUM = 203423744;  // 4 B
  const size_t NEED     = 203423748;

  if (ws_size < NEED) {
    diag_kernel<<<1, 64, 0, stream>>>((float*)d_out, (float)(ws_size >> 20));
    return;
  }

  char* ws = (char*)d_ws;
  __hip_bfloat16* xbf  = (__hip_bfloat16*)(ws + OFF_XBF);
  __hip_bfloat16* wdbf = (__hip_bfloat16*)(ws + OFF_WDBF);
  __hip_bfloat16* wubf = (__hip_bfloat16*)(ws + OFF_WUBF);
  __hip_bfloat16* wgbf = (__hip_bfloat16*)(ws + OFF_WGBF);
  __hip_bfloat16* wcbf = (__hip_bfloat16*)(ws + OFF_WCBF);
  __hip_bfloat16* sp   = (__hip_bfloat16*)(ws + OFF_SP);
  __hip_bfloat16* h    = (__hip_bfloat16*)(ws + OFF_H);
  float*          pred = (float*)         (ws + OFF_H);   // aliases h (dead by then)
  float*          vsum = (float*)         (ws + OFF_VSUM);

  hipMemsetAsync(vsum, 0, sizeof(float), stream);

  cvt_bf16<<<(MROWS * DD / 8 + 255) / 256, 256, 0, stream>>>(x, xbf, MROWS * DD / 8);
  cvt_bf16<<<(DN * DD / 8 + 255) / 256, 256, 0, stream>>>(Wdown, wdbf, DN * DD / 8);
  cvt_bf16<<<(DN * DN / 8 + 255) / 256, 256, 0, stream>>>(Wca3, wcbf, DN * DN / 8);
  cvt_bf16<<<(DD * DN / 8 + 255) / 256, 256, 0, stream>>>(Wup, wubf, DD * DN / 8);
  cvt_bf16<<<(DD * DD / 8 + 255) / 256, 256, 0, stream>>>(Wgate, wgbf, DD * DD / 8);

  // h1 = relu(x @ W_down.T) -> bf16   [256^2 8-phase, grid 32*16=512]
  gemm_bt8<1><<<(MROWS >> 8) * (DN >> 8), 512, 131072, stream>>>(
      xbf, wdbf, h, MROWS, DN, DD, nullptr);
  // sparse = kwta(h1)/norm
  kwta_kernel<0><<<MROWS, 256, 0, stream>>>(h, sp, nullptr, kptr);
  // h2 = relu(sparse @ W_ca3.T) -> bf16, global sum -> vsum   [256^2 8-phase]
  gemm_bt8<2><<<(MROWS >> 8) * (DN >> 8), 512, 131072, stream>>>(
      sp, wcbf, h, MROWS, DN, DN, vsum);
  // successor = valid ? kwta(h2)/norm : sparse (in-place in sp)
  kwta_kernel<1><<<MROWS, 256, 0, stream>>>(h, sp, vsum, kptr);
  // pred = successor @ W_up.T (f32, overwrites h region)   [128^2, grid 512]
  gemm_bt<0><<<(MROWS >> 7) * (DD >> 7), 256, 0, stream>>>(
      sp, wubf, pred, MROWS, DD, DN, nullptr, nullptr, nullptr);
  // out = x + sigmoid(x @ W_gate.T + b_gate) * pred   [128^2]
  gemm_bt<3><<<(MROWS >> 7) * (DD >> 7), 256, 0, stream>>>(
      xbf, wgbf, (float*)d_out, MROWS, DD, DD, x, pred, bgate);
}

// Round 4
// 549.070 us; speedup vs baseline: 1.3397x; 1.2359x over previous
//
#include <hip/hip_runtime.h>
#include <hip/hip_bf16.h>

typedef __bf16 bf16x8 __attribute__((ext_vector_type(8)));
typedef float f32x4 __attribute__((ext_vector_type(4)));

#define MROWS 8192
#define DD 1024
#define DN 4096

__device__ __forceinline__ void load_lds16(const void* g, void* l) {
  __builtin_amdgcn_global_load_lds((const __attribute__((address_space(1))) void*)g,
                                   (__attribute__((address_space(3))) void*)l, 16, 0, 0);
}

__device__ __forceinline__ unsigned f32_to_bf16_rne(float f) {
  unsigned u = __float_as_uint(f);
  return (u + 0x7fffu + ((u >> 16) & 1u)) >> 16;
}

// ============================================================================
// 256x256 8-phase GEMM (m201-style): C[M,N] = A[M,K] @ B[N,K]^T, A,B bf16.
// 512 threads = 8 waves (2M x 4N); per-wave output 128x64 (8x4 frags 16x16).
// Counted vmcnt(4) at phases 4/8 only; never drains to 0 in the loop.
// EPI: 1 = relu->bf16, 2 = relu->bf16 + block sum -> atomicAdd(vsum)
// ============================================================================
template<int EPI>
__global__ void __launch_bounds__(512, 1)
gemm_bt8(const __hip_bfloat16* __restrict__ A, const __hip_bfloat16* __restrict__ B,
         __hip_bfloat16* __restrict__ Cb, int M, int N, int K,
         float* __restrict__ vsum)
{
  extern __shared__ __align__(16) char smem[];
  const int tid  = threadIdx.x;
  const int lane = tid & 63;
  const int wave = tid >> 6;
  const int wm = wave >> 2;   // 0..1
  const int wn = wave & 3;    // 0..3

  // XCD-aware swizzle (grid % 8 == 0 for all our launches)
  const int nwg = gridDim.x;
  const int bid = ((int)blockIdx.x % 8) * (nwg >> 3) + ((int)blockIdx.x >> 3);

  const int nbn = N >> 8;
  const int bm = (bid / nbn) << 8;
  const int bn = (bid % nbn) << 8;

  const int NT = K >> 6;  // K-tiles (power of two)

  f32x4 acc[8][4];
  const f32x4 zero = {0.f, 0.f, 0.f, 0.f};
#pragma unroll
  for (int i = 0; i < 8; ++i)
#pragma unroll
    for (int j = 0; j < 4; ++j)
      acc[i][j] = zero;

  // staging: thread covers row tid>>2 (+128 on 2nd issue), LDS chunk tid&3;
  // source chunk pre-swizzled by (row>>1)&3 = (tid>>3)&3.
  const int cs8 = (((tid & 3) ^ ((tid >> 3) & 3)) << 3);
  const __hip_bfloat16* Ag = A + (size_t)(bm + (tid >> 2)) * K + cs8;
  const __hip_bfloat16* Bg = B + (size_t)(bn + (tid >> 2)) * K + cs8;

  // fragment reads: row = base + rl, k-chunk kc, swizzle (rl>>1)&3
  const int rl = lane & 15;
  const int kc = lane >> 4;
  const int chunk_off = ((kc ^ ((rl >> 1) & 3)) << 4);
  const int aoff = ((wm << 7) + rl) * 64 + chunk_off;
  const int boff = ((wn << 6) + rl) * 64 + chunk_off;

#define STAGE_A(S, KH) do { \
    const int kt_ = (((S) & (NT - 1)) << 6) + ((KH) << 5); \
    char* dst_ = smem + (((((S) & 1) << 1) | (KH)) << 14) + (tid << 4); \
    load_lds16(Ag + kt_, dst_); \
    load_lds16(Ag + (size_t)128 * K + kt_, dst_ + 8192); \
  } while (0)

#define STAGE_B(S, KH) do { \
    const int kt_ = (((S) & (NT - 1)) << 6) + ((KH) << 5); \
    char* dst_ = smem + 65536 + (((((S) & 1) << 1) | (KH)) << 14) + (tid << 4); \
    load_lds16(Bg + kt_, dst_); \
    load_lds16(Bg + (size_t)128 * K + kt_, dst_ + 8192); \
  } while (0)

  bf16x8 af0, af1, af2, af3, bf0, bf1, bf2, bf3;

#define DS_A(P, KH, MH) do { \
    const char* ab_ = smem + ((((P) << 1) | (KH)) << 14) + aoff + (MH) * 4096; \
    af0 = *(const bf16x8*)(ab_); \
    af1 = *(const bf16x8*)(ab_ + 1024); \
    af2 = *(const bf16x8*)(ab_ + 2048); \
    af3 = *(const bf16x8*)(ab_ + 3072); \
  } while (0)

#define DS_B(P, KH) do { \
    const char* bb_ = smem + 65536 + ((((P) << 1) | (KH)) << 14) + boff; \
    bf0 = *(const bf16x8*)(bb_); \
    bf1 = *(const bf16x8*)(bb_ + 1024); \
    bf2 = *(const bf16x8*)(bb_ + 2048); \
    bf3 = *(const bf16x8*)(bb_ + 3072); \
  } while (0)

#define MFMA_ROW(MI, AF) \
    acc[MI][0] = __builtin_amdgcn_mfma_f32_16x16x32_bf16(AF, bf0, acc[MI][0], 0, 0, 0); \
    acc[MI][1] = __builtin_amdgcn_mfma_f32_16x16x32_bf16(AF, bf1, acc[MI][1], 0, 0, 0); \
    acc[MI][2] = __builtin_amdgcn_mfma_f32_16x16x32_bf16(AF, bf2, acc[MI][2], 0, 0, 0); \
    acc[MI][3] = __builtin_amdgcn_mfma_f32_16x16x32_bf16(AF, bf3, acc[MI][3], 0, 0, 0);

#define PH(P, KH, MH, STG, VM) do { \
    DS_A(P, KH, MH); \
    if ((MH) == 0) { DS_B(P, KH); } \
    STG; \
    if (VM) { asm volatile("s_waitcnt vmcnt(4)" ::: "memory"); } \
    asm volatile("s_barrier" ::: "memory"); \
    asm volatile("s_waitcnt lgkmcnt(0)" ::: "memory"); \
    __builtin_amdgcn_sched_barrier(0); \
    __builtin_amdgcn_s_setprio(1); \
    MFMA_ROW((MH) * 4 + 0, af0) \
    MFMA_ROW((MH) * 4 + 1, af1) \
    MFMA_ROW((MH) * 4 + 2, af2) \
    MFMA_ROW((MH) * 4 + 3, af3) \
    __builtin_amdgcn_s_setprio(0); \
    asm volatile("s_barrier" ::: "memory"); \
  } while (0)

  STAGE_A(0, 0); STAGE_B(0, 0);
  STAGE_A(0, 1); STAGE_B(0, 1);
  STAGE_A(1, 0); STAGE_B(1, 0);
  asm volatile("s_waitcnt vmcnt(4)" ::: "memory");
  asm volatile("s_barrier" ::: "memory");

  for (int t = 0; t < NT; t += 2) {
    PH(0, 0, 0, STAGE_A(t + 1, 1), 0);
    PH(0, 0, 1, STAGE_B(t + 1, 1), 0);
    PH(0, 1, 0, STAGE_A(t + 2, 0), 0);
    PH(0, 1, 1, STAGE_B(t + 2, 0), 1);
    PH(1, 0, 0, STAGE_A(t + 2, 1), 0);
    PH(1, 0, 1, STAGE_B(t + 2, 1), 0);
    PH(1, 1, 0, STAGE_A(t + 3, 0), 0);
    PH(1, 1, 1, STAGE_B(t + 3, 0), 1);
  }

  // epilogue: C/D frag layout col = lane&15, row = (lane>>4)*4 + q
  const int r0 = bm + (wm << 7) + (kc << 2);
  const int c0 = bn + (wn << 6) + rl;
  float lsum = 0.f;
#pragma unroll
  for (int mi = 0; mi < 8; ++mi) {
#pragma unroll
    for (int nf = 0; nf < 4; ++nf) {
#pragma unroll
      for (int q = 0; q < 4; ++q) {
        const int r = r0 + (mi << 4) + q;
        const int c = c0 + (nf << 4);
        float v = fmaxf(acc[mi][nf][q], 0.f);
        Cb[(size_t)r * N + c] = __float2bfloat16(v);
        if constexpr (EPI == 2) lsum += v;
      }
    }
  }
  if constexpr (EPI == 2) {
#pragma unroll
    for (int off = 32; off > 0; off >>= 1)
      lsum += __shfl_down(lsum, off);
    if (lane == 0) atomicAdd(vsum, lsum);
  }

#undef STAGE_A
#undef STAGE_B
#undef DS_A
#undef DS_B
#undef MFMA_ROW
#undef PH
}

// ============================================================================
// 128x128 2-barrier GEMM (m97-style) — for N=1024 outputs (grid density).
// EPI: 0 = bf16 store (pred), 3 = final: out = x + sigmoid(v+b)*pred (f32)
// ============================================================================
template<int EPI>
__global__ void __launch_bounds__(256)
gemm_bt(const __hip_bfloat16* __restrict__ A, const __hip_bfloat16* __restrict__ B,
        void* __restrict__ Cv, int M, int N, int K,
        const float* __restrict__ Xf, const __hip_bfloat16* __restrict__ PredBf,
        const float* __restrict__ Bgate)
{
  __shared__ __align__(16) char smem[32768];
  const int tid  = threadIdx.x;
  const int lane = tid & 63;
  const int wave = tid >> 6;

  const int nbn = N >> 7;
  const int bm = ((int)blockIdx.x / nbn) << 7;
  const int bn = ((int)blockIdx.x % nbn) << 7;

  const int wm = (wave >> 1) << 6;
  const int wn = (wave & 1) << 6;

  const f32x4 zero = {0.f, 0.f, 0.f, 0.f};
  f32x4 acc[4][4];
#pragma unroll
  for (int i = 0; i < 4; ++i)
#pragma unroll
    for (int j = 0; j < 4; ++j)
      acc[i][j] = zero;

  const int srow = tid >> 3;
  const int schk = (tid & 7) ^ (srow & 7);
  const __hip_bfloat16* Ag = A + (size_t)(bm + srow) * K + (schk << 3);
  const __hip_bfloat16* Bg = B + (size_t)(bn + srow) * K + (schk << 3);
  char* ldsA = smem + (wave << 10);
  char* ldsB = smem + 16384 + (wave << 10);

  const int aoff0 = (wm + (lane & 15)) << 7;
  const int boff0 = 16384 + ((wn + (lane & 15)) << 7);
  const int kc = lane >> 4;
  const int sw = lane & 7;

  for (int k0 = 0; k0 < K; k0 += 64) {
#pragma unroll
    for (int i = 0; i < 4; ++i)
      load_lds16(Ag + (size_t)(i << 5) * K + k0, ldsA + (i << 12));
#pragma unroll
    for (int i = 0; i < 4; ++i)
      load_lds16(Bg + (size_t)(i << 5) * K + k0, ldsB + (i << 12));
    __syncthreads();
#pragma unroll
    for (int ks = 0; ks < 2; ++ks) {
      const int cb = ((kc + (ks << 2)) ^ sw) << 4;
      bf16x8 af[4], bfr[4];
#pragma unroll
      for (int i = 0; i < 4; ++i)
        af[i] = *reinterpret_cast<const bf16x8*>(smem + aoff0 + (i << 11) + cb);
#pragma unroll
      for (int j = 0; j < 4; ++j)
        bfr[j] = *reinterpret_cast<const bf16x8*>(smem + boff0 + (j << 11) + cb);
#pragma unroll
      for (int i = 0; i < 4; ++i)
#pragma unroll
        for (int j = 0; j < 4; ++j)
          acc[i][j] = __builtin_amdgcn_mfma_f32_16x16x32_bf16(af[i], bfr[j], acc[i][j], 0, 0, 0);
    }
    __syncthreads();
  }

  float* Cf = (float*)Cv;
  __hip_bfloat16* Cb = (__hip_bfloat16*)Cv;
  const int r0 = bm + wm + ((lane >> 4) << 2);
  const int c0 = bn + wn + (lane & 15);
#pragma unroll
  for (int i = 0; i < 4; ++i) {
#pragma unroll
    for (int j = 0; j < 4; ++j) {
#pragma unroll
      for (int q = 0; q < 4; ++q) {
        const int r = r0 + (i << 4) + q;
        const int c = c0 + (j << 4);
        const size_t idx = (size_t)r * N + c;
        float v = acc[i][j][q];
        if constexpr (EPI == 0) {
          Cb[idx] = __float2bfloat16(v);
        } else {
          const float g = 1.f / (1.f + __expf(-(v + Bgate[c])));
          Cf[idx] = Xf[idx] + g * __bfloat162float(PredBf[idx]);
        }
      }
    }
  }
}

// ============================================================================
// kwta, wave-per-row, barrier-free. Row = 4096 nonneg bf16 (u16 keys, order-
// preserving). All values register-resident (8 x uint4 / lane). 2-pass 8-bit
// radix select over wave-private 256-bin LDS hist; zeros skipped (if nz < k,
// thresh = 0 analytically). Suffix-scan via shfl_down; select via ballot.
// Keep v >= thresh; normalize by ||kept||.
// MODE 0: OUT = kept/norm.  MODE 1: OUT = valid ? kept/norm : OUT (unchanged).
// ============================================================================
template<int MODE>
__global__ void __launch_bounds__(256)
kwta_wave(const __hip_bfloat16* __restrict__ H, __hip_bfloat16* __restrict__ OUT,
          const float* __restrict__ vsumPtr, const int* __restrict__ kptr)
{
  __shared__ unsigned hist[4 * 256];
  const int tid  = threadIdx.x;
  const int lane = tid & 63;
  const int w    = tid >> 6;
  const int row  = ((int)blockIdx.x << 2) + w;
  unsigned* wh = hist + (w << 8);

  if constexpr (MODE == 1) {
    if (!(*vsumPtr >= 1e-10f)) return;  // successor = sparse (already in OUT)
  }

  const uint4* h8 = (const uint4*)(H + (size_t)row * 4096);
  uint4 d[8];
#pragma unroll
  for (int i = 0; i < 8; ++i) d[i] = h8[(i << 6) + lane];

  const unsigned k = (unsigned)(*kptr);

  // nonzero count (zeros can never be counted in the radix passes)
  unsigned nz = 0;
#pragma unroll
  for (int i = 0; i < 8; ++i) {
    const unsigned* p = (const unsigned*)&d[i];
#pragma unroll
    for (int c = 0; c < 4; ++c) {
      nz += (p[c] & 0xffffu) ? 1u : 0u;
      nz += (p[c] >> 16) ? 1u : 0u;
    }
  }
#pragma unroll
  for (int off = 32; off > 0; off >>= 1) nz += __shfl_xor(nz, off);

  unsigned threshKey = 0;
  if (nz >= k) {
    unsigned rem = k;
    unsigned pfx = 0;
    for (int pass = 0; pass < 2; ++pass) {
      // zero wave-private hist (4 bins/lane, one uint4)
      *(uint4*)(wh + (lane << 2)) = make_uint4(0u, 0u, 0u, 0u);
      __builtin_amdgcn_wave_barrier();
      asm volatile("s_waitcnt lgkmcnt(0)" ::: "memory");
      __builtin_amdgcn_sched_barrier(0);
#pragma unroll
      for (int i = 0; i < 8; ++i) {
        const unsigned* p = (const unsigned*)&d[i];
#pragma unroll
        for (int c = 0; c < 4; ++c) {
#pragma unroll
          for (int hh = 0; hh < 2; ++hh) {
            const unsigned key = hh ? (p[c] >> 16) : (p[c] & 0xffffu);
            const bool ok = (key != 0u) && (pass == 0 || (key >> 8) == pfx);
            if (ok) atomicAdd(&wh[pass == 0 ? (key >> 8) : (key & 0xffu)], 1u);
          }
        }
      }
      __builtin_amdgcn_wave_barrier();
      asm volatile("s_waitcnt lgkmcnt(0)" ::: "memory");
      __builtin_amdgcn_sched_barrier(0);
      // suffix scan over 256 bins (lane owns bins 4l..4l+3)
      const uint4 hv = *(const uint4*)(wh + (lane << 2));
      const unsigned b0 = hv.x, b1 = hv.y, b2 = hv.z, b3 = hv.w;
      unsigned s = b0 + b1 + b2 + b3;
#pragma unroll
      for (int off = 1; off < 64; off <<= 1) {
        const unsigned t = __shfl_down(s, off);
        if (lane + off < 64) s += t;
      }
      const unsigned ge0 = s;
      const unsigned ge1 = s - b0;
      const unsigned ge2 = ge1 - b1;
      const unsigned ge3 = ge2 - b2;
      const unsigned gt3 = ge3 - b3;
      const bool m0 = (ge1 < rem) & (rem <= ge0);
      const bool m1 = (ge2 < rem) & (rem <= ge1);
      const bool m2 = (ge3 < rem) & (rem <= ge2);
      const bool m3 = (gt3 < rem) & (rem <= ge3);
      unsigned mybin, mygt;
      if (m0)      { mybin = 0; mygt = ge1; }
      else if (m1) { mybin = 1; mygt = ge2; }
      else if (m2) { mybin = 2; mygt = ge3; }
      else         { mybin = 3; mygt = gt3; }
      const unsigned long long bal = __ballot(m0 | m1 | m2 | m3);
      const int src = __ffsll((long long)bal) - 1;
      const unsigned sel = __shfl((lane << 2) + mybin, src);
      rem = __shfl(rem - mygt, src);
      pfx = (pass == 0) ? sel : ((pfx << 8) | sel);
    }
    threshKey = pfx;
  }

  // sum of squares over kept values
  float ss = 0.f;
#pragma unroll
  for (int i = 0; i < 8; ++i) {
    const unsigned* p = (const unsigned*)&d[i];
#pragma unroll
    for (int c = 0; c < 4; ++c) {
#pragma unroll
      for (int hh = 0; hh < 2; ++hh) {
        const unsigned key = hh ? (p[c] >> 16) : (p[c] & 0xffffu);
        if (key >= threshKey) {
          const float v = __uint_as_float(key << 16);
          ss = fmaf(v, v, ss);
        }
      }
    }
  }
#pragma unroll
  for (int off = 32; off > 0; off >>= 1) ss += __shfl_xor(ss, off);
  const float inv = 1.f / fmaxf(sqrtf(ss), 1e-10f);

  uint4* o8 = (uint4*)(OUT + (size_t)row * 4096);
#pragma unroll
  for (int i = 0; i < 8; ++i) {
    const unsigned* p = (const unsigned*)&d[i];
    uint4 o;
    unsigned* q = (unsigned*)&o;
#pragma unroll
    for (int c = 0; c < 4; ++c) {
      const unsigned lo = p[c] & 0xffffu, hi = p[c] >> 16;
      unsigned rlo = 0u, rhi = 0u;
      if (lo >= threshKey) rlo = f32_to_bf16_rne(__uint_as_float(lo << 16) * inv);
      if (hi >= threshKey) rhi = f32_to_bf16_rne(__uint_as_float(hi << 16) * inv);
      q[c] = (rhi << 16) | rlo;
    }
    o8[(i << 6) + lane] = o;
  }
}

// Fused f32 -> bf16 conversion of all 5 arrays (8 elems / thread).
__global__ void __launch_bounds__(256)
cvt_all(const float* __restrict__ x,  const float* __restrict__ wd,
        const float* __restrict__ wc, const float* __restrict__ wu,
        const float* __restrict__ wg,
        __hip_bfloat16* __restrict__ xo,  __hip_bfloat16* __restrict__ wdo,
        __hip_bfloat16* __restrict__ wco, __hip_bfloat16* __restrict__ wuo,
        __hip_bfloat16* __restrict__ wgo)
{
  const int i = blockIdx.x * 256 + threadIdx.x;
  const int C0 = 1048576, C1 = 1572864, C2 = 3670016, C3 = 4194304, C4 = 4325376;
  const float* in; __hip_bfloat16* out; int off;
  if      (i < C0) { in = x;  out = xo;  off = i; }
  else if (i < C1) { in = wd; out = wdo; off = i - C0; }
  else if (i < C2) { in = wc; out = wco; off = i - C1; }
  else if (i < C3) { in = wu; out = wuo; off = i - C2; }
  else if (i < C4) { in = wg; out = wgo; off = i - C3; }
  else return;
  const float4 a = ((const float4*)in)[2 * off];
  const float4 b = ((const float4*)in)[2 * off + 1];
  unsigned r0 = (f32_to_bf16_rne(a.y) << 16) | f32_to_bf16_rne(a.x);
  unsigned r1 = (f32_to_bf16_rne(a.w) << 16) | f32_to_bf16_rne(a.z);
  unsigned r2 = (f32_to_bf16_rne(b.y) << 16) | f32_to_bf16_rne(b.x);
  unsigned r3 = (f32_to_bf16_rne(b.w) << 16) | f32_to_bf16_rne(b.z);
  ((uint4*)out)[off] = make_uint4(r0, r1, r2, r3);
}

__global__ void diag_kernel(float* out, float mb)
{
  if (threadIdx.x == 0 && blockIdx.x == 0) out[0] = -mb;
}

extern "C" void kernel_launch(void* const* d_in, const int* in_sizes, int n_in,
                              void* d_out, int out_size, void* d_ws, size_t ws_size,
                              hipStream_t stream)
{
  const float* x     = (const float*)d_in[0]; // (8192,1024)
  const float* Wdown = (const float*)d_in[1]; // (4096,1024)
  const float* Wup   = (const float*)d_in[2]; // (1024,4096)
  const float* Wgate = (const float*)d_in[3]; // (1024,1024)
  const float* bgate = (const float*)d_in[4]; // (1024,)
  const float* Wca3  = (const float*)d_in[5]; // (4096,4096)
  const int*   kptr  = (const int*)d_in[6];

  const size_t OFF_XBF  = 0;          // 16 MB bf16 x
  const size_t OFF_WDBF = 16777216;   //  8 MB bf16 W_down
  const size_t OFF_WUBF = 25165824;   //  8 MB bf16 W_up
  const size_t OFF_WGBF = 33554432;   //  2 MB bf16 W_gate
  const size_t OFF_WCBF = 35651584;   // 32 MB bf16 W_ca3
  const size_t OFF_SP   = 69206016;   // 64 MB bf16 sparse/successor
  const size_t OFF_H    = 136314880;  // 64 MB bf16 h1/h2; pred (16 MB bf16) aliases
  const size_t OFF_VSUM = 203423744;  // 4 B
  const size_t NEED     = 203423748;

  if (ws_size < NEED) {
    diag_kernel<<<1, 64, 0, stream>>>((float*)d_out, (float)(ws_size >> 20));
    return;
  }

  char* ws = (char*)d_ws;
  __hip_bfloat16* xbf  = (__hip_bfloat16*)(ws + OFF_XBF);
  __hip_bfloat16* wdbf = (__hip_bfloat16*)(ws + OFF_WDBF);
  __hip_bfloat16* wubf = (__hip_bfloat16*)(ws + OFF_WUBF);
  __hip_bfloat16* wgbf = (__hip_bfloat16*)(ws + OFF_WGBF);
  __hip_bfloat16* wcbf = (__hip_bfloat16*)(ws + OFF_WCBF);
  __hip_bfloat16* sp   = (__hip_bfloat16*)(ws + OFF_SP);
  __hip_bfloat16* h    = (__hip_bfloat16*)(ws + OFF_H);
  __hip_bfloat16* pred = (__hip_bfloat16*)(ws + OFF_H);   // aliases h (dead by then)
  float*          vsum = (float*)         (ws + OFF_VSUM);

  hipMemsetAsync(vsum, 0, sizeof(float), stream);

  // all f32 -> bf16 conversions in one launch (4325376 8-elem items)
  cvt_all<<<16896, 256, 0, stream>>>(x, Wdown, Wca3, Wup, Wgate,
                                     xbf, wdbf, wcbf, wubf, wgbf);

  // h1 = relu(x @ W_down.T) -> bf16   [256^2 8-phase, grid 512]
  gemm_bt8<1><<<(MROWS >> 8) * (DN >> 8), 512, 131072, stream>>>(
      xbf, wdbf, h, MROWS, DN, DD, nullptr);
  // sparse = kwta(h1)/norm   [wave-per-row]
  kwta_wave<0><<<MROWS / 4, 256, 0, stream>>>(h, sp, nullptr, kptr);
  // h2 = relu(sparse @ W_ca3.T) -> bf16, global sum -> vsum   [256^2 8-phase]
  gemm_bt8<2><<<(MROWS >> 8) * (DN >> 8), 512, 131072, stream>>>(
      sp, wcbf, h, MROWS, DN, DN, vsum);
  // successor = valid ? kwta(h2)/norm : sparse (in-place in sp)
  kwta_wave<1><<<MROWS / 4, 256, 0, stream>>>(h, sp, vsum, kptr);
  // pred = successor @ W_up.T -> bf16   [128^2, grid 512]
  gemm_bt<0><<<(MROWS >> 7) * (DD >> 7), 256, 0, stream>>>(
      sp, wubf, pred, MROWS, DD, DN, nullptr, nullptr, nullptr);
  // out = x + sigmoid(x @ W_gate.T + b_gate) * pred   [128^2]
  gemm_bt<3><<<(MROWS >> 7) * (DD >> 7), 256, 0, stream>>>(
      xbf, wgbf, (float*)d_out, MROWS, DD, DD, x, pred, bgate);
}

// Round 5
// 545.084 us; speedup vs baseline: 1.3495x; 1.0073x over previous
//
#include <hip/hip_runtime.h>
#include <hip/hip_bf16.h>

typedef __bf16 bf16x8 __attribute__((ext_vector_type(8)));
typedef float f32x4 __attribute__((ext_vector_type(4)));

#define MROWS 8192
#define DD 1024
#define DN 4096

__device__ __forceinline__ void load_lds16(const void* g, void* l) {
  __builtin_amdgcn_global_load_lds((const __attribute__((address_space(1))) void*)g,
                                   (__attribute__((address_space(3))) void*)l, 16, 0, 0);
}

__device__ __forceinline__ unsigned f32_to_bf16_rne(float f) {
  unsigned u = __float_as_uint(f);
  return (u + 0x7fffu + ((u >> 16) & 1u)) >> 16;
}

// ============================================================================
// 256x256 8-phase GEMM (m201-style): C[M,N] = A[M,K] @ B[N,K]^T, A,B bf16.
// 512 threads = 8 waves (2M x 4N); per-wave output 128x64 (8x4 frags 16x16).
// DEEP PIPELINE: vmcnt(8) at the end of every even phase -> 4 half-tiles
// (8 loads) in flight; each staged load gets ~5 phases to land. Derivation:
// reads of phase p consume stages issued >= 5 stage-slots earlier, so
// "all but 8 newest loads landed" always covers them (incl. prologue edge).
// EPI: 1 = relu->bf16, 2 = relu->bf16 + block sum -> atomicAdd(vsum)
// ============================================================================
template<int EPI>
__global__ void __launch_bounds__(512, 1)
gemm_bt8(const __hip_bfloat16* __restrict__ A, const __hip_bfloat16* __restrict__ B,
         __hip_bfloat16* __restrict__ Cb, int M, int N, int K,
         float* __restrict__ vsum)
{
  extern __shared__ __align__(16) char smem[];
  const int tid  = threadIdx.x;
  const int lane = tid & 63;
  const int wave = tid >> 6;
  const int wm = wave >> 2;   // 0..1
  const int wn = wave & 3;    // 0..3

  // XCD-aware swizzle (grid % 8 == 0 for all our launches)
  const int nwg = gridDim.x;
  const int bid = ((int)blockIdx.x % 8) * (nwg >> 3) + ((int)blockIdx.x >> 3);

  const int nbn = N >> 8;
  const int bm = (bid / nbn) << 8;
  const int bn = (bid % nbn) << 8;

  const int NT = K >> 6;  // K-tiles (power of two)

  f32x4 acc[8][4];
  const f32x4 zero = {0.f, 0.f, 0.f, 0.f};
#pragma unroll
  for (int i = 0; i < 8; ++i)
#pragma unroll
    for (int j = 0; j < 4; ++j)
      acc[i][j] = zero;

  // staging: thread covers row tid>>2 (+128 on 2nd issue), LDS chunk tid&3;
  // source chunk pre-swizzled by (row>>1)&3 = (tid>>3)&3.
  const int cs8 = (((tid & 3) ^ ((tid >> 3) & 3)) << 3);
  const __hip_bfloat16* Ag = A + (size_t)(bm + (tid >> 2)) * K + cs8;
  const __hip_bfloat16* Bg = B + (size_t)(bn + (tid >> 2)) * K + cs8;

  // fragment reads: row = base + rl, k-chunk kc, swizzle (rl>>1)&3
  const int rl = lane & 15;
  const int kc = lane >> 4;
  const int chunk_off = ((kc ^ ((rl >> 1) & 3)) << 4);
  const int aoff = ((wm << 7) + rl) * 64 + chunk_off;
  const int boff = ((wn << 6) + rl) * 64 + chunk_off;

#define STAGE_A(S, KH) do { \
    const int kt_ = (((S) & (NT - 1)) << 6) + ((KH) << 5); \
    char* dst_ = smem + (((((S) & 1) << 1) | (KH)) << 14) + (tid << 4); \
    load_lds16(Ag + kt_, dst_); \
    load_lds16(Ag + (size_t)128 * K + kt_, dst_ + 8192); \
  } while (0)

#define STAGE_B(S, KH) do { \
    const int kt_ = (((S) & (NT - 1)) << 6) + ((KH) << 5); \
    char* dst_ = smem + 65536 + (((((S) & 1) << 1) | (KH)) << 14) + (tid << 4); \
    load_lds16(Bg + kt_, dst_); \
    load_lds16(Bg + (size_t)128 * K + kt_, dst_ + 8192); \
  } while (0)

  bf16x8 af0, af1, af2, af3, bf0, bf1, bf2, bf3;

#define DS_A(P, KH, MH) do { \
    const char* ab_ = smem + ((((P) << 1) | (KH)) << 14) + aoff + (MH) * 4096; \
    af0 = *(const bf16x8*)(ab_); \
    af1 = *(const bf16x8*)(ab_ + 1024); \
    af2 = *(const bf16x8*)(ab_ + 2048); \
    af3 = *(const bf16x8*)(ab_ + 3072); \
  } while (0)

#define DS_B(P, KH) do { \
    const char* bb_ = smem + 65536 + ((((P) << 1) | (KH)) << 14) + boff; \
    bf0 = *(const bf16x8*)(bb_); \
    bf1 = *(const bf16x8*)(bb_ + 1024); \
    bf2 = *(const bf16x8*)(bb_ + 2048); \
    bf3 = *(const bf16x8*)(bb_ + 3072); \
  } while (0)

#define MFMA_ROW(MI, AF) \
    acc[MI][0] = __builtin_amdgcn_mfma_f32_16x16x32_bf16(AF, bf0, acc[MI][0], 0, 0, 0); \
    acc[MI][1] = __builtin_amdgcn_mfma_f32_16x16x32_bf16(AF, bf1, acc[MI][1], 0, 0, 0); \
    acc[MI][2] = __builtin_amdgcn_mfma_f32_16x16x32_bf16(AF, bf2, acc[MI][2], 0, 0, 0); \
    acc[MI][3] = __builtin_amdgcn_mfma_f32_16x16x32_bf16(AF, bf3, acc[MI][3], 0, 0, 0);

#define PH(P, KH, MH, STG, VM) do { \
    DS_A(P, KH, MH); \
    if ((MH) == 0) { DS_B(P, KH); } \
    STG; \
    if (VM) { asm volatile("s_waitcnt vmcnt(8)" ::: "memory"); } \
    asm volatile("s_barrier" ::: "memory"); \
    asm volatile("s_waitcnt lgkmcnt(0)" ::: "memory"); \
    __builtin_amdgcn_sched_barrier(0); \
    __builtin_amdgcn_s_setprio(1); \
    MFMA_ROW((MH) * 4 + 0, af0) \
    MFMA_ROW((MH) * 4 + 1, af1) \
    MFMA_ROW((MH) * 4 + 2, af2) \
    MFMA_ROW((MH) * 4 + 3, af3) \
    __builtin_amdgcn_s_setprio(0); \
    asm volatile("s_barrier" ::: "memory"); \
  } while (0)

  // prologue: 6 half-tiles staged (12 loads); vmcnt(4) -> tile0 fully landed,
  // A(1,0)/B(1,0) (4 loads) still in flight entering the loop.
  STAGE_A(0, 0); STAGE_B(0, 0);
  STAGE_A(0, 1); STAGE_B(0, 1);
  STAGE_A(1, 0); STAGE_B(1, 0);
  asm volatile("s_waitcnt vmcnt(4)" ::: "memory");
  asm volatile("s_barrier" ::: "memory");

  // main loop: 2 K-tiles per iter; tail stages wrap via &(NT-1) (never read).
  // vmcnt(8) every even phase: phase-by-phase audit (2 loads/stage):
  //  end ph2: out={pA(t,1),pB(t,1),pA(t+1,0),pB(t+1,0),A(t+1,1),B(t+1,1)}=12
  //           -> waits 4 oldest: (t,1) landed, needed ph3,4  OK
  //  end ph4: waits until pA(t+1,0),pB(t+1,0) landed, needed ph5,6  OK
  //  end ph6: waits until A(t+1,1),B(t+1,1) landed, needed ph7,8  OK
  //  end ph8: waits until A(t+2,0),B(t+2,0) landed, needed next ph1,2  OK
  for (int t = 0; t < NT; t += 2) {
    PH(0, 0, 0, STAGE_A(t + 1, 1), 0);
    PH(0, 0, 1, STAGE_B(t + 1, 1), 1);
    PH(0, 1, 0, STAGE_A(t + 2, 0), 0);
    PH(0, 1, 1, STAGE_B(t + 2, 0), 1);
    PH(1, 0, 0, STAGE_A(t + 2, 1), 0);
    PH(1, 0, 1, STAGE_B(t + 2, 1), 1);
    PH(1, 1, 0, STAGE_A(t + 3, 0), 0);
    PH(1, 1, 1, STAGE_B(t + 3, 0), 1);
  }

  // epilogue: C/D frag layout col = lane&15, row = (lane>>4)*4 + q
  const int r0 = bm + (wm << 7) + (kc << 2);
  const int c0 = bn + (wn << 6) + rl;
  float lsum = 0.f;
#pragma unroll
  for (int mi = 0; mi < 8; ++mi) {
#pragma unroll
    for (int nf = 0; nf < 4; ++nf) {
#pragma unroll
      for (int q = 0; q < 4; ++q) {
        const int r = r0 + (mi << 4) + q;
        const int c = c0 + (nf << 4);
        float v = fmaxf(acc[mi][nf][q], 0.f);
        Cb[(size_t)r * N + c] = __float2bfloat16(v);
        if constexpr (EPI == 2) lsum += v;
      }
    }
  }
  if constexpr (EPI == 2) {
#pragma unroll
    for (int off = 32; off > 0; off >>= 1)
      lsum += __shfl_down(lsum, off);
    if (lane == 0) atomicAdd(vsum, lsum);
  }

#undef STAGE_A
#undef STAGE_B
#undef DS_A
#undef DS_B
#undef MFMA_ROW
#undef PH
}

// ============================================================================
// 128x128 2-barrier GEMM (m97-style) — for N=1024 outputs (grid density).
// EPI: 0 = bf16 store (pred), 3 = final: out = x + sigmoid(v+b)*pred (f32)
// ============================================================================
template<int EPI>
__global__ void __launch_bounds__(256)
gemm_bt(const __hip_bfloat16* __restrict__ A, const __hip_bfloat16* __restrict__ B,
        void* __restrict__ Cv, int M, int N, int K,
        const float* __restrict__ Xf, const __hip_bfloat16* __restrict__ PredBf,
        const float* __restrict__ Bgate)
{
  __shared__ __align__(16) char smem[32768];
  const int tid  = threadIdx.x;
  const int lane = tid & 63;
  const int wave = tid >> 6;

  const int nbn = N >> 7;
  const int bm = ((int)blockIdx.x / nbn) << 7;
  const int bn = ((int)blockIdx.x % nbn) << 7;

  const int wm = (wave >> 1) << 6;
  const int wn = (wave & 1) << 6;

  const f32x4 zero = {0.f, 0.f, 0.f, 0.f};
  f32x4 acc[4][4];
#pragma unroll
  for (int i = 0; i < 4; ++i)
#pragma unroll
    for (int j = 0; j < 4; ++j)
      acc[i][j] = zero;

  const int srow = tid >> 3;
  const int schk = (tid & 7) ^ (srow & 7);
  const __hip_bfloat16* Ag = A + (size_t)(bm + srow) * K + (schk << 3);
  const __hip_bfloat16* Bg = B + (size_t)(bn + srow) * K + (schk << 3);
  char* ldsA = smem + (wave << 10);
  char* ldsB = smem + 16384 + (wave << 10);

  const int aoff0 = (wm + (lane & 15)) << 7;
  const int boff0 = 16384 + ((wn + (lane & 15)) << 7);
  const int kc = lane >> 4;
  const int sw = lane & 7;

  for (int k0 = 0; k0 < K; k0 += 64) {
#pragma unroll
    for (int i = 0; i < 4; ++i)
      load_lds16(Ag + (size_t)(i << 5) * K + k0, ldsA + (i << 12));
#pragma unroll
    for (int i = 0; i < 4; ++i)
      load_lds16(Bg + (size_t)(i << 5) * K + k0, ldsB + (i << 12));
    __syncthreads();
#pragma unroll
    for (int ks = 0; ks < 2; ++ks) {
      const int cb = ((kc + (ks << 2)) ^ sw) << 4;
      bf16x8 af[4], bfr[4];
#pragma unroll
      for (int i = 0; i < 4; ++i)
        af[i] = *reinterpret_cast<const bf16x8*>(smem + aoff0 + (i << 11) + cb);
#pragma unroll
      for (int j = 0; j < 4; ++j)
        bfr[j] = *reinterpret_cast<const bf16x8*>(smem + boff0 + (j << 11) + cb);
#pragma unroll
      for (int i = 0; i < 4; ++i)
#pragma unroll
        for (int j = 0; j < 4; ++j)
          acc[i][j] = __builtin_amdgcn_mfma_f32_16x16x32_bf16(af[i], bfr[j], acc[i][j], 0, 0, 0);
    }
    __syncthreads();
  }

  float* Cf = (float*)Cv;
  __hip_bfloat16* Cb = (__hip_bfloat16*)Cv;
  const int r0 = bm + wm + ((lane >> 4) << 2);
  const int c0 = bn + wn + (lane & 15);
#pragma unroll
  for (int i = 0; i < 4; ++i) {
#pragma unroll
    for (int j = 0; j < 4; ++j) {
#pragma unroll
      for (int q = 0; q < 4; ++q) {
        const int r = r0 + (i << 4) + q;
        const int c = c0 + (j << 4);
        const size_t idx = (size_t)r * N + c;
        float v = acc[i][j][q];
        if constexpr (EPI == 0) {
          Cb[idx] = __float2bfloat16(v);
        } else {
          const float g = 1.f / (1.f + __expf(-(v + Bgate[c])));
          Cf[idx] = Xf[idx] + g * __bfloat162float(PredBf[idx]);
        }
      }
    }
  }
}

// ============================================================================
// kwta, wave-per-row, no LDS / no atomics / no barriers. Row = 4096 nonneg
// bf16 (u16 keys, order-preserving). Values register-resident (8 uint4/lane).
// Exact threshold via 16-step binary search: largest T with count(key>=T)>=k
// == k-th largest value (ties kept, matching top_k + where semantics).
// T stays 0 when fewer than k nonzeros -> keep all (matches reference).
// MODE 0: OUT = kept/norm.  MODE 1: OUT = valid ? kept/norm : OUT (unchanged).
// ============================================================================
template<int MODE>
__global__ void __launch_bounds__(256)
kwta_wave(const __hip_bfloat16* __restrict__ H, __hip_bfloat16* __restrict__ OUT,
          const float* __restrict__ vsumPtr, const int* __restrict__ kptr)
{
  const int tid  = threadIdx.x;
  const int lane = tid & 63;
  const int w    = tid >> 6;
  const int row  = ((int)blockIdx.x << 2) + w;

  if constexpr (MODE == 1) {
    if (!(*vsumPtr >= 1e-10f)) return;  // successor = sparse (already in OUT)
  }

  const uint4* h8 = (const uint4*)(H + (size_t)row * 4096);
  uint4 d[8];
#pragma unroll
  for (int i = 0; i < 8; ++i) d[i] = h8[(i << 6) + lane];

  const unsigned k = (unsigned)(*kptr);

  // binary search: invariant cnt(lo) >= k (cnt(0)=4096), cnt(hi) < k
  unsigned lo = 0, hi = 65536;
#pragma unroll 1
  for (int it = 0; it < 16; ++it) {
    const unsigned mid = (lo + hi) >> 1;
    unsigned c = 0;
#pragma unroll
    for (int i = 0; i < 8; ++i) {
      const unsigned* p = (const unsigned*)&d[i];
#pragma unroll
      for (int c4 = 0; c4 < 4; ++c4) {
        c += ((p[c4] & 0xffffu) >= mid) ? 1u : 0u;
        c += ((p[c4] >> 16) >= mid) ? 1u : 0u;
      }
    }
#pragma unroll
    for (int off = 32; off > 0; off >>= 1) c += __shfl_xor(c, off);
    if (c >= k) lo = mid; else hi = mid;
  }
  const unsigned threshKey = lo;

  // sum of squares over kept values
  float ss = 0.f;
#pragma unroll
  for (int i = 0; i < 8; ++i) {
    const unsigned* p = (const unsigned*)&d[i];
#pragma unroll
    for (int c4 = 0; c4 < 4; ++c4) {
#pragma unroll
      for (int hh = 0; hh < 2; ++hh) {
        const unsigned key = hh ? (p[c4] >> 16) : (p[c4] & 0xffffu);
        if (key >= threshKey) {
          const float v = __uint_as_float(key << 16);
          ss = fmaf(v, v, ss);
        }
      }
    }
  }
#pragma unroll
  for (int off = 32; off > 0; off >>= 1) ss += __shfl_xor(ss, off);
  const float inv = 1.f / fmaxf(sqrtf(ss), 1e-10f);

  uint4* o8 = (uint4*)(OUT + (size_t)row * 4096);
#pragma unroll
  for (int i = 0; i < 8; ++i) {
    const unsigned* p = (const unsigned*)&d[i];
    uint4 o;
    unsigned* q = (unsigned*)&o;
#pragma unroll
    for (int c4 = 0; c4 < 4; ++c4) {
      const unsigned lov = p[c4] & 0xffffu, hiv = p[c4] >> 16;
      unsigned rlo = 0u, rhi = 0u;
      if (lov >= threshKey) rlo = f32_to_bf16_rne(__uint_as_float(lov << 16) * inv);
      if (hiv >= threshKey) rhi = f32_to_bf16_rne(__uint_as_float(hiv << 16) * inv);
      q[c4] = (rhi << 16) | rlo;
    }
    o8[(i << 6) + lane] = o;
  }
}

// Fused f32 -> bf16 conversion of all 5 arrays (8 elems / thread).
__global__ void __launch_bounds__(256)
cvt_all(const float* __restrict__ x,  const float* __restrict__ wd,
        const float* __restrict__ wc, const float* __restrict__ wu,
        const float* __restrict__ wg,
        __hip_bfloat16* __restrict__ xo,  __hip_bfloat16* __restrict__ wdo,
        __hip_bfloat16* __restrict__ wco, __hip_bfloat16* __restrict__ wuo,
        __hip_bfloat16* __restrict__ wgo)
{
  const int i = blockIdx.x * 256 + threadIdx.x;
  const int C0 = 1048576, C1 = 1572864, C2 = 3670016, C3 = 4194304, C4 = 4325376;
  const float* in; __hip_bfloat16* out; int off;
  if      (i < C0) { in = x;  out = xo;  off = i; }
  else if (i < C1) { in = wd; out = wdo; off = i - C0; }
  else if (i < C2) { in = wc; out = wco; off = i - C1; }
  else if (i < C3) { in = wu; out = wuo; off = i - C2; }
  else if (i < C4) { in = wg; out = wgo; off = i - C3; }
  else return;
  const float4 a = ((const float4*)in)[2 * off];
  const float4 b = ((const float4*)in)[2 * off + 1];
  unsigned r0 = (f32_to_bf16_rne(a.y) << 16) | f32_to_bf16_rne(a.x);
  unsigned r1 = (f32_to_bf16_rne(a.w) << 16) | f32_to_bf16_rne(a.z);
  unsigned r2 = (f32_to_bf16_rne(b.y) << 16) | f32_to_bf16_rne(b.x);
  unsigned r3 = (f32_to_bf16_rne(b.w) << 16) | f32_to_bf16_rne(b.z);
  ((uint4*)out)[off] = make_uint4(r0, r1, r2, r3);
}

__global__ void diag_kernel(float* out, float mb)
{
  if (threadIdx.x == 0 && blockIdx.x == 0) out[0] = -mb;
}

extern "C" void kernel_launch(void* const* d_in, const int* in_sizes, int n_in,
                              void* d_out, int out_size, void* d_ws, size_t ws_size,
                              hipStream_t stream)
{
  const float* x     = (const float*)d_in[0]; // (8192,1024)
  const float* Wdown = (const float*)d_in[1]; // (4096,1024)
  const float* Wup   = (const float*)d_in[2]; // (1024,4096)
  const float* Wgate = (const float*)d_in[3]; // (1024,1024)
  const float* bgate = (const float*)d_in[4]; // (1024,)
  const float* Wca3  = (const float*)d_in[5]; // (4096,4096)
  const int*   kptr  = (const int*)d_in[6];

  const size_t OFF_XBF  = 0;          // 16 MB bf16 x
  const size_t OFF_WDBF = 16777216;   //  8 MB bf16 W_down
  const size_t OFF_WUBF = 25165824;   //  8 MB bf16 W_up
  const size_t OFF_WGBF = 33554432;   //  2 MB bf16 W_gate
  const size_t OFF_WCBF = 35651584;   // 32 MB bf16 W_ca3
  const size_t OFF_SP   = 69206016;   // 64 MB bf16 sparse/successor
  const size_t OFF_H    = 136314880;  // 64 MB bf16 h1/h2; pred (16 MB bf16) aliases
  const size_t OFF_VSUM = 203423744;  // 4 B
  const size_t NEED     = 203423748;

  if (ws_size < NEED) {
    diag_kernel<<<1, 64, 0, stream>>>((float*)d_out, (float)(ws_size >> 20));
    return;
  }

  char* ws = (char*)d_ws;
  __hip_bfloat16* xbf  = (__hip_bfloat16*)(ws + OFF_XBF);
  __hip_bfloat16* wdbf = (__hip_bfloat16*)(ws + OFF_WDBF);
  __hip_bfloat16* wubf = (__hip_bfloat16*)(ws + OFF_WUBF);
  __hip_bfloat16* wgbf = (__hip_bfloat16*)(ws + OFF_WGBF);
  __hip_bfloat16* wcbf = (__hip_bfloat16*)(ws + OFF_WCBF);
  __hip_bfloat16* sp   = (__hip_bfloat16*)(ws + OFF_SP);
  __hip_bfloat16* h    = (__hip_bfloat16*)(ws + OFF_H);
  __hip_bfloat16* pred = (__hip_bfloat16*)(ws + OFF_H);   // aliases h (dead by then)
  float*          vsum = (float*)         (ws + OFF_VSUM);

  hipMemsetAsync(vsum, 0, sizeof(float), stream);

  // all f32 -> bf16 conversions in one launch (4325376 8-elem items)
  cvt_all<<<16896, 256, 0, stream>>>(x, Wdown, Wca3, Wup, Wgate,
                                     xbf, wdbf, wcbf, wubf, wgbf);

  // h1 = relu(x @ W_down.T) -> bf16   [256^2 8-phase, grid 512]
  gemm_bt8<1><<<(MROWS >> 8) * (DN >> 8), 512, 131072, stream>>>(
      xbf, wdbf, h, MROWS, DN, DD, nullptr);
  // sparse = kwta(h1)/norm   [wave-per-row binary search]
  kwta_wave<0><<<MROWS / 4, 256, 0, stream>>>(h, sp, nullptr, kptr);
  // h2 = relu(sparse @ W_ca3.T) -> bf16, global sum -> vsum   [256^2 8-phase]
  gemm_bt8<2><<<(MROWS >> 8) * (DN >> 8), 512, 131072, stream>>>(
      sp, wcbf, h, MROWS, DN, DN, vsum);
  // successor = valid ? kwta(h2)/norm : sparse (in-place in sp)
  kwta_wave<1><<<MROWS / 4, 256, 0, stream>>>(h, sp, vsum, kptr);
  // pred = successor @ W_up.T -> bf16   [128^2, grid 512]
  gemm_bt<0><<<(MROWS >> 7) * (DD >> 7), 256, 0, stream>>>(
      sp, wubf, pred, MROWS, DD, DN, nullptr, nullptr, nullptr);
  // out = x + sigmoid(x @ W_gate.T + b_gate) * pred   [128^2]
  gemm_bt<3><<<(MROWS >> 7) * (DD >> 7), 256, 0, stream>>>(
      xbf, wgbf, (float*)d_out, MROWS, DD, DD, x, pred, bgate);
}

// Round 6
// 538.872 us; speedup vs baseline: 1.3651x; 1.0115x over previous
//
#include <hip/hip_runtime.h>
#include <hip/hip_bf16.h>

typedef __bf16 bf16x8 __attribute__((ext_vector_type(8)));
typedef float f32x4 __attribute__((ext_vector_type(4)));

#define MROWS 8192
#define DD 1024
#define DN 4096

__device__ __forceinline__ void load_lds16(const void* g, void* l) {
  __builtin_amdgcn_global_load_lds((const __attribute__((address_space(1))) void*)g,
                                   (__attribute__((address_space(3))) void*)l, 16, 0, 0);
}

__device__ __forceinline__ unsigned f32_to_bf16_rne(float f) {
  unsigned u = __float_as_uint(f);
  return (u + 0x7fffu + ((u >> 16) & 1u)) >> 16;
}

// ============================================================================
// 256x256 8-phase GEMM, PIPELINED FRAGMENT READS: each phase ds_reads the
// NEXT phase's A-frags (alternate reg set) at phase top, so their LDS latency
// hides under this phase's stage+barrier+MFMA. B-frags re-read after the MFMA
// cluster (B consumed last) to avoid a second B reg set. No explicit
// lgkmcnt(0): compiler emits counted lgkmcnt(4) for the 1-phase-old frags.
// vmcnt(6) at every odd phase end exactly confirms each half-tile before its
// first (shifted) read — audited per phase, incl. prologue (vmcnt(4) after 6
// half-tiles staged).
// EPI: 1 = relu->bf16, 2 = relu->bf16 + block sum -> atomicAdd(vsum)
// ============================================================================
template<int EPI>
__global__ void __launch_bounds__(512, 1)
gemm_bt8(const __hip_bfloat16* __restrict__ A, const __hip_bfloat16* __restrict__ B,
         __hip_bfloat16* __restrict__ Cb, int M, int N, int K,
         float* __restrict__ vsum)
{
  extern __shared__ __align__(16) char smem[];
  const int tid  = threadIdx.x;
  const int lane = tid & 63;
  const int wave = tid >> 6;
  const int wm = wave >> 2;   // 0..1
  const int wn = wave & 3;    // 0..3

  // XCD-aware swizzle (grid % 8 == 0 for all our launches)
  const int nwg = gridDim.x;
  const int bid = ((int)blockIdx.x % 8) * (nwg >> 3) + ((int)blockIdx.x >> 3);

  const int nbn = N >> 8;
  const int bm = (bid / nbn) << 8;
  const int bn = (bid % nbn) << 8;

  const int NT = K >> 6;  // K-tiles (power of two)

  f32x4 acc[8][4];
  const f32x4 zero = {0.f, 0.f, 0.f, 0.f};
#pragma unroll
  for (int i = 0; i < 8; ++i)
#pragma unroll
    for (int j = 0; j < 4; ++j)
      acc[i][j] = zero;

  // staging: thread covers row tid>>2 (+128 on 2nd issue), LDS chunk tid&3;
  // source chunk pre-swizzled by (row>>1)&3 = (tid>>3)&3.
  const int cs8 = (((tid & 3) ^ ((tid >> 3) & 3)) << 3);
  const __hip_bfloat16* Ag = A + (size_t)(bm + (tid >> 2)) * K + cs8;
  const __hip_bfloat16* Bg = B + (size_t)(bn + (tid >> 2)) * K + cs8;

  // fragment reads: row = base + rl, k-chunk kc, swizzle (rl>>1)&3
  const int rl = lane & 15;
  const int kc = lane >> 4;
  const int chunk_off = ((kc ^ ((rl >> 1) & 3)) << 4);
  const int aoff = ((wm << 7) + rl) * 64 + chunk_off;
  const int boff = ((wn << 6) + rl) * 64 + chunk_off;

#define STAGE_A(S, KH) do { \
    const int kt_ = (((S) & (NT - 1)) << 6) + ((KH) << 5); \
    char* dst_ = smem + (((((S) & 1) << 1) | (KH)) << 14) + (tid << 4); \
    load_lds16(Ag + kt_, dst_); \
    load_lds16(Ag + (size_t)128 * K + kt_, dst_ + 8192); \
  } while (0)

#define STAGE_B(S, KH) do { \
    const int kt_ = (((S) & (NT - 1)) << 6) + ((KH) << 5); \
    char* dst_ = smem + 65536 + (((((S) & 1) << 1) | (KH)) << 14) + (tid << 4); \
    load_lds16(Bg + kt_, dst_); \
    load_lds16(Bg + (size_t)128 * K + kt_, dst_ + 8192); \
  } while (0)

  bf16x8 afS[2][4];           // double-buffered A frags (const-indexed only)
  bf16x8 bf0, bf1, bf2, bf3;  // single-buffered B frags

#define MFMA_ROW(MI, AF) \
    acc[MI][0] = __builtin_amdgcn_mfma_f32_16x16x32_bf16(AF, bf0, acc[MI][0], 0, 0, 0); \
    acc[MI][1] = __builtin_amdgcn_mfma_f32_16x16x32_bf16(AF, bf1, acc[MI][1], 0, 0, 0); \
    acc[MI][2] = __builtin_amdgcn_mfma_f32_16x16x32_bf16(AF, bf2, acc[MI][2], 0, 0, 0); \
    acc[MI][3] = __builtin_amdgcn_mfma_f32_16x16x32_bf16(AF, bf3, acc[MI][3], 0, 0, 0);

// PN/KHN/MHN: slot+half of the NEXT phase's A-frags, written into afS[ASETN].
// ACUR: reg set consumed by this phase's MFMA. MHC: acc quadrant (0/1).
// DOBP: after MFMA, re-read B-frags for the next phase pair from (BP,BKH).
// VM: emit s_waitcnt vmcnt(6) before barrier-1 (odd phases).
#define PH(PN, KHN, MHN, ASETN, ACUR, MHC, DOBP, BP, BKH, STG, VM) do { \
    { const char* ab_ = smem + ((((PN) << 1) | (KHN)) << 14) + aoff + (MHN) * 4096; \
      afS[ASETN][0] = *(const bf16x8*)(ab_); \
      afS[ASETN][1] = *(const bf16x8*)(ab_ + 1024); \
      afS[ASETN][2] = *(const bf16x8*)(ab_ + 2048); \
      afS[ASETN][3] = *(const bf16x8*)(ab_ + 3072); } \
    STG; \
    if (VM) { asm volatile("s_waitcnt vmcnt(6)" ::: "memory"); } \
    asm volatile("s_barrier" ::: "memory"); \
    __builtin_amdgcn_sched_barrier(0); \
    __builtin_amdgcn_s_setprio(1); \
    MFMA_ROW((MHC) * 4 + 0, afS[ACUR][0]) \
    MFMA_ROW((MHC) * 4 + 1, afS[ACUR][1]) \
    MFMA_ROW((MHC) * 4 + 2, afS[ACUR][2]) \
    MFMA_ROW((MHC) * 4 + 3, afS[ACUR][3]) \
    __builtin_amdgcn_s_setprio(0); \
    if (DOBP) { \
      const char* bb_ = smem + 65536 + ((((BP) << 1) | (BKH)) << 14) + boff; \
      bf0 = *(const bf16x8*)(bb_); bf1 = *(const bf16x8*)(bb_ + 1024); \
      bf2 = *(const bf16x8*)(bb_ + 2048); bf3 = *(const bf16x8*)(bb_ + 3072); } \
    asm volatile("s_barrier" ::: "memory"); \
  } while (0)

  // prologue: stage tile0 + tile1 khalf0 (6 half-tiles, 12 loads);
  // vmcnt(4) -> tile0 fully confirmed; fill ph1's frags (slot(0,0) MH0 + B).
  STAGE_A(0, 0); STAGE_B(0, 0);
  STAGE_A(0, 1); STAGE_B(0, 1);
  STAGE_A(1, 0); STAGE_B(1, 0);
  asm volatile("s_waitcnt vmcnt(4)" ::: "memory");
  asm volatile("s_barrier" ::: "memory");
  {
    const char* ab_ = smem + aoff;           // slot(0,0) MH0
    afS[1][0] = *(const bf16x8*)(ab_);
    afS[1][1] = *(const bf16x8*)(ab_ + 1024);
    afS[1][2] = *(const bf16x8*)(ab_ + 2048);
    afS[1][3] = *(const bf16x8*)(ab_ + 3072);
    const char* bb_ = smem + 65536 + boff;   // slot(0,0)
    bf0 = *(const bf16x8*)(bb_); bf1 = *(const bf16x8*)(bb_ + 1024);
    bf2 = *(const bf16x8*)(bb_ + 2048); bf3 = *(const bf16x8*)(bb_ + 3072);
  }

  // wait-audit (vmcnt(6) @ odd phases, reads shifted 1 phase early):
  //  ph1 vm -> confirms through prev-ph6 stage: covers ph2-top A(0,1) + ph2-post B(0,1)
  //  ph3 vm -> through prev-ph8: covers ph4-top A(1,0) + ph4-post B(1,0)
  //  ph5 vm -> through this-ph2: covers ph6-top A(1,1) + ph6-post B(1,1)
  //  ph7 vm -> through this-ph4: covers ph8-top A(0,0)' + ph8-post B(0,0)'
#pragma unroll 1
  for (int t = 0; t < NT; t += 2) {
    PH(0, 0, 1, 0, 1, 0, 0, 0, 0, STAGE_A(t + 1, 1), 1); // ph1
    PH(0, 1, 0, 1, 0, 1, 1, 0, 1, STAGE_B(t + 1, 1), 0); // ph2
    PH(0, 1, 1, 0, 1, 0, 0, 0, 0, STAGE_A(t + 2, 0), 1); // ph3
    PH(1, 0, 0, 1, 0, 1, 1, 1, 0, STAGE_B(t + 2, 0), 0); // ph4
    PH(1, 0, 1, 0, 1, 0, 0, 0, 0, STAGE_A(t + 2, 1), 1); // ph5
    PH(1, 1, 0, 1, 0, 1, 1, 1, 1, STAGE_B(t + 2, 1), 0); // ph6
    PH(1, 1, 1, 0, 1, 0, 0, 0, 0, STAGE_A(t + 3, 0), 1); // ph7
    PH(0, 0, 0, 1, 0, 1, 1, 0, 0, STAGE_B(t + 3, 0), 0); // ph8
  }

  // epilogue: C/D frag layout col = lane&15, row = (lane>>4)*4 + q
  const int r0 = bm + (wm << 7) + (kc << 2);
  const int c0 = bn + (wn << 6) + rl;
  float lsum = 0.f;
#pragma unroll
  for (int mi = 0; mi < 8; ++mi) {
#pragma unroll
    for (int nf = 0; nf < 4; ++nf) {
#pragma unroll
      for (int q = 0; q < 4; ++q) {
        const int r = r0 + (mi << 4) + q;
        const int c = c0 + (nf << 4);
        float v = fmaxf(acc[mi][nf][q], 0.f);
        Cb[(size_t)r * N + c] = __float2bfloat16(v);
        if constexpr (EPI == 2) lsum += v;
      }
    }
  }
  if constexpr (EPI == 2) {
#pragma unroll
    for (int off = 32; off > 0; off >>= 1)
      lsum += __shfl_down(lsum, off);
    if (lane == 0) atomicAdd(vsum, lsum);
  }

#undef STAGE_A
#undef STAGE_B
#undef MFMA_ROW
#undef PH
}

// ============================================================================
// 128x128 2-barrier GEMM (m97-style) — for N=1024 outputs (grid density).
// EPI: 0 = bf16 store (pred), 3 = final: out = x + sigmoid(v+b)*pred (f32)
// ============================================================================
template<int EPI>
__global__ void __launch_bounds__(256)
gemm_bt(const __hip_bfloat16* __restrict__ A, const __hip_bfloat16* __restrict__ B,
        void* __restrict__ Cv, int M, int N, int K,
        const float* __restrict__ Xf, const __hip_bfloat16* __restrict__ PredBf,
        const float* __restrict__ Bgate)
{
  __shared__ __align__(16) char smem[32768];
  const int tid  = threadIdx.x;
  const int lane = tid & 63;
  const int wave = tid >> 6;

  const int nbn = N >> 7;
  const int bm = ((int)blockIdx.x / nbn) << 7;
  const int bn = ((int)blockIdx.x % nbn) << 7;

  const int wm = (wave >> 1) << 6;
  const int wn = (wave & 1) << 6;

  const f32x4 zero = {0.f, 0.f, 0.f, 0.f};
  f32x4 acc[4][4];
#pragma unroll
  for (int i = 0; i < 4; ++i)
#pragma unroll
    for (int j = 0; j < 4; ++j)
      acc[i][j] = zero;

  const int srow = tid >> 3;
  const int schk = (tid & 7) ^ (srow & 7);
  const __hip_bfloat16* Ag = A + (size_t)(bm + srow) * K + (schk << 3);
  const __hip_bfloat16* Bg = B + (size_t)(bn + srow) * K + (schk << 3);
  char* ldsA = smem + (wave << 10);
  char* ldsB = smem + 16384 + (wave << 10);

  const int aoff0 = (wm + (lane & 15)) << 7;
  const int boff0 = 16384 + ((wn + (lane & 15)) << 7);
  const int kc = lane >> 4;
  const int sw = lane & 7;

  for (int k0 = 0; k0 < K; k0 += 64) {
#pragma unroll
    for (int i = 0; i < 4; ++i)
      load_lds16(Ag + (size_t)(i << 5) * K + k0, ldsA + (i << 12));
#pragma unroll
    for (int i = 0; i < 4; ++i)
      load_lds16(Bg + (size_t)(i << 5) * K + k0, ldsB + (i << 12));
    __syncthreads();
#pragma unroll
    for (int ks = 0; ks < 2; ++ks) {
      const int cb = ((kc + (ks << 2)) ^ sw) << 4;
      bf16x8 af[4], bfr[4];
#pragma unroll
      for (int i = 0; i < 4; ++i)
        af[i] = *reinterpret_cast<const bf16x8*>(smem + aoff0 + (i << 11) + cb);
#pragma unroll
      for (int j = 0; j < 4; ++j)
        bfr[j] = *reinterpret_cast<const bf16x8*>(smem + boff0 + (j << 11) + cb);
#pragma unroll
      for (int i = 0; i < 4; ++i)
#pragma unroll
        for (int j = 0; j < 4; ++j)
          acc[i][j] = __builtin_amdgcn_mfma_f32_16x16x32_bf16(af[i], bfr[j], acc[i][j], 0, 0, 0);
    }
    __syncthreads();
  }

  float* Cf = (float*)Cv;
  __hip_bfloat16* Cb = (__hip_bfloat16*)Cv;
  const int r0 = bm + wm + ((lane >> 4) << 2);
  const int c0 = bn + wn + (lane & 15);
#pragma unroll
  for (int i = 0; i < 4; ++i) {
#pragma unroll
    for (int j = 0; j < 4; ++j) {
#pragma unroll
      for (int q = 0; q < 4; ++q) {
        const int r = r0 + (i << 4) + q;
        const int c = c0 + (j << 4);
        const size_t idx = (size_t)r * N + c;
        float v = acc[i][j][q];
        if constexpr (EPI == 0) {
          Cb[idx] = __float2bfloat16(v);
        } else {
          const float g = 1.f / (1.f + __expf(-(v + Bgate[c])));
          Cf[idx] = Xf[idx] + g * __bfloat162float(PredBf[idx]);
        }
      }
    }
  }
}

// ============================================================================
// kwta, wave-per-row, no LDS / no atomics / no barriers. Row = 4096 nonneg
// bf16 (u16 keys, order-preserving). Values register-resident (8 uint4/lane).
// Exact threshold via 16-step binary search: largest T with count(key>=T)>=k.
// MODE 0: OUT = kept/norm.  MODE 1: OUT = valid ? kept/norm : OUT (unchanged).
// ============================================================================
template<int MODE>
__global__ void __launch_bounds__(256)
kwta_wave(const __hip_bfloat16* __restrict__ H, __hip_bfloat16* __restrict__ OUT,
          const float* __restrict__ vsumPtr, const int* __restrict__ kptr)
{
  const int tid  = threadIdx.x;
  const int lane = tid & 63;
  const int w    = tid >> 6;
  const int row  = ((int)blockIdx.x << 2) + w;

  if constexpr (MODE == 1) {
    if (!(*vsumPtr >= 1e-10f)) return;  // successor = sparse (already in OUT)
  }

  const uint4* h8 = (const uint4*)(H + (size_t)row * 4096);
  uint4 d[8];
#pragma unroll
  for (int i = 0; i < 8; ++i) d[i] = h8[(i << 6) + lane];

  const unsigned k = (unsigned)(*kptr);

  // binary search: invariant cnt(lo) >= k (cnt(0)=4096), cnt(hi) < k
  unsigned lo = 0, hi = 65536;
#pragma unroll 1
  for (int it = 0; it < 16; ++it) {
    const unsigned mid = (lo + hi) >> 1;
    unsigned c = 0;
#pragma unroll
    for (int i = 0; i < 8; ++i) {
      const unsigned* p = (const unsigned*)&d[i];
#pragma unroll
      for (int c4 = 0; c4 < 4; ++c4) {
        c += ((p[c4] & 0xffffu) >= mid) ? 1u : 0u;
        c += ((p[c4] >> 16) >= mid) ? 1u : 0u;
      }
    }
#pragma unroll
    for (int off = 32; off > 0; off >>= 1) c += __shfl_xor(c, off);
    if (c >= k) lo = mid; else hi = mid;
  }
  const unsigned threshKey = lo;

  // sum of squares over kept values
  float ss = 0.f;
#pragma unroll
  for (int i = 0; i < 8; ++i) {
    const unsigned* p = (const unsigned*)&d[i];
#pragma unroll
    for (int c4 = 0; c4 < 4; ++c4) {
#pragma unroll
      for (int hh = 0; hh < 2; ++hh) {
        const unsigned key = hh ? (p[c4] >> 16) : (p[c4] & 0xffffu);
        if (key >= threshKey) {
          const float v = __uint_as_float(key << 16);
          ss = fmaf(v, v, ss);
        }
      }
    }
  }
#pragma unroll
  for (int off = 32; off > 0; off >>= 1) ss += __shfl_xor(ss, off);
  const float inv = 1.f / fmaxf(sqrtf(ss), 1e-10f);

  uint4* o8 = (uint4*)(OUT + (size_t)row * 4096);
#pragma unroll
  for (int i = 0; i < 8; ++i) {
    const unsigned* p = (const unsigned*)&d[i];
    uint4 o;
    unsigned* q = (unsigned*)&o;
#pragma unroll
    for (int c4 = 0; c4 < 4; ++c4) {
      const unsigned lov = p[c4] & 0xffffu, hiv = p[c4] >> 16;
      unsigned rlo = 0u, rhi = 0u;
      if (lov >= threshKey) rlo = f32_to_bf16_rne(__uint_as_float(lov << 16) * inv);
      if (hiv >= threshKey) rhi = f32_to_bf16_rne(__uint_as_float(hiv << 16) * inv);
      q[c4] = (rhi << 16) | rlo;
    }
    o8[(i << 6) + lane] = o;
  }
}

// Fused f32 -> bf16 conversion of all 5 arrays (8 elems / thread).
__global__ void __launch_bounds__(256)
cvt_all(const float* __restrict__ x,  const float* __restrict__ wd,
        const float* __restrict__ wc, const float* __restrict__ wu,
        const float* __restrict__ wg,
        __hip_bfloat16* __restrict__ xo,  __hip_bfloat16* __restrict__ wdo,
        __hip_bfloat16* __restrict__ wco, __hip_bfloat16* __restrict__ wuo,
        __hip_bfloat16* __restrict__ wgo)
{
  const int i = blockIdx.x * 256 + threadIdx.x;
  const int C0 = 1048576, C1 = 1572864, C2 = 3670016, C3 = 4194304, C4 = 4325376;
  const float* in; __hip_bfloat16* out; int off;
  if      (i < C0) { in = x;  out = xo;  off = i; }
  else if (i < C1) { in = wd; out = wdo; off = i - C0; }
  else if (i < C2) { in = wc; out = wco; off = i - C1; }
  else if (i < C3) { in = wu; out = wuo; off = i - C2; }
  else if (i < C4) { in = wg; out = wgo; off = i - C3; }
  else return;
  const float4 a = ((const float4*)in)[2 * off];
  const float4 b = ((const float4*)in)[2 * off + 1];
  unsigned r0 = (f32_to_bf16_rne(a.y) << 16) | f32_to_bf16_rne(a.x);
  unsigned r1 = (f32_to_bf16_rne(a.w) << 16) | f32_to_bf16_rne(a.z);
  unsigned r2 = (f32_to_bf16_rne(b.y) << 16) | f32_to_bf16_rne(b.x);
  unsigned r3 = (f32_to_bf16_rne(b.w) << 16) | f32_to_bf16_rne(b.z);
  ((uint4*)out)[off] = make_uint4(r0, r1, r2, r3);
}

__global__ void diag_kernel(float* out, float mb)
{
  if (threadIdx.x == 0 && blockIdx.x == 0) out[0] = -mb;
}

extern "C" void kernel_launch(void* const* d_in, const int* in_sizes, int n_in,
                              void* d_out, int out_size, void* d_ws, size_t ws_size,
                              hipStream_t stream)
{
  const float* x     = (const float*)d_in[0]; // (8192,1024)
  const float* Wdown = (const float*)d_in[1]; // (4096,1024)
  const float* Wup   = (const float*)d_in[2]; // (1024,4096)
  const float* Wgate = (const float*)d_in[3]; // (1024,1024)
  const float* bgate = (const float*)d_in[4]; // (1024,)
  const float* Wca3  = (const float*)d_in[5]; // (4096,4096)
  const int*   kptr  = (const int*)d_in[6];

  const size_t OFF_XBF  = 0;          // 16 MB bf16 x
  const size_t OFF_WDBF = 16777216;   //  8 MB bf16 W_down
  const size_t OFF_WUBF = 25165824;   //  8 MB bf16 W_up
  const size_t OFF_WGBF = 33554432;   //  2 MB bf16 W_gate
  const size_t OFF_WCBF = 35651584;   // 32 MB bf16 W_ca3
  const size_t OFF_SP   = 69206016;   // 64 MB bf16 sparse/successor
  const size_t OFF_H    = 136314880;  // 64 MB bf16 h1/h2; pred (16 MB bf16) aliases
  const size_t OFF_VSUM = 203423744;  // 4 B
  const size_t NEED     = 203423748;

  if (ws_size < NEED) {
    diag_kernel<<<1, 64, 0, stream>>>((float*)d_out, (float)(ws_size >> 20));
    return;
  }

  char* ws = (char*)d_ws;
  __hip_bfloat16* xbf  = (__hip_bfloat16*)(ws + OFF_XBF);
  __hip_bfloat16* wdbf = (__hip_bfloat16*)(ws + OFF_WDBF);
  __hip_bfloat16* wubf = (__hip_bfloat16*)(ws + OFF_WUBF);
  __hip_bfloat16* wgbf = (__hip_bfloat16*)(ws + OFF_WGBF);
  __hip_bfloat16* wcbf = (__hip_bfloat16*)(ws + OFF_WCBF);
  __hip_bfloat16* sp   = (__hip_bfloat16*)(ws + OFF_SP);
  __hip_bfloat16* h    = (__hip_bfloat16*)(ws + OFF_H);
  __hip_bfloat16* pred = (__hip_bfloat16*)(ws + OFF_H);   // aliases h (dead by then)
  float*          vsum = (float*)         (ws + OFF_VSUM);

  hipMemsetAsync(vsum, 0, sizeof(float), stream);

  // all f32 -> bf16 conversions in one launch (4325376 8-elem items)
  cvt_all<<<16896, 256, 0, stream>>>(x, Wdown, Wca3, Wup, Wgate,
                                     xbf, wdbf, wcbf, wubf, wgbf);

  // h1 = relu(x @ W_down.T) -> bf16   [256^2 8-phase pipelined, grid 512]
  gemm_bt8<1><<<(MROWS >> 8) * (DN >> 8), 512, 131072, stream>>>(
      xbf, wdbf, h, MROWS, DN, DD, nullptr);
  // sparse = kwta(h1)/norm   [wave-per-row binary search]
  kwta_wave<0><<<MROWS / 4, 256, 0, stream>>>(h, sp, nullptr, kptr);
  // h2 = relu(sparse @ W_ca3.T) -> bf16, global sum -> vsum
  gemm_bt8<2><<<(MROWS >> 8) * (DN >> 8), 512, 131072, stream>>>(
      sp, wcbf, h, MROWS, DN, DN, vsum);
  // successor = valid ? kwta(h2)/norm : sparse (in-place in sp)
  kwta_wave<1><<<MROWS / 4, 256, 0, stream>>>(h, sp, vsum, kptr);
  // pred = successor @ W_up.T -> bf16   [128^2, grid 512]
  gemm_bt<0><<<(MROWS >> 7) * (DD >> 7), 256, 0, stream>>>(
      sp, wubf, pred, MROWS, DD, DN, nullptr, nullptr, nullptr);
  // out = x + sigmoid(x @ W_gate.T + b_gate) * pred   [128^2]
  gemm_bt<3><<<(MROWS >> 7) * (DD >> 7), 256, 0, stream>>>(
      xbf, wgbf, (float*)d_out, MROWS, DD, DD, x, pred, bgate);
}

// Round 7
// 448.709 us; speedup vs baseline: 1.6394x; 1.2009x over previous
//
#include <hip/hip_runtime.h>
#include <hip/hip_bf16.h>
#include <stdint.h>

typedef __bf16 bf16x8 __attribute__((ext_vector_type(8)));
typedef float f32x4 __attribute__((ext_vector_type(4)));
typedef int i32x4 __attribute__((ext_vector_type(4)));

#define MROWS 8192
#define DD 1024
#define DN 4096

__device__ __forceinline__ void load_lds16(const void* g, void* l) {
  __builtin_amdgcn_global_load_lds((const __attribute__((address_space(1))) void*)g,
                                   (__attribute__((address_space(3))) void*)l, 16, 0, 0);
}

__device__ __forceinline__ unsigned f32_to_bf16_rne(float f) {
  unsigned u = __float_as_uint(f);
  return (u + 0x7fffu + ((u >> 16) & 1u)) >> 16;
}

// ============================================================================
// 256x256 8-phase bf16 GEMM (round-6 pipelined schedule, verified) — h1 only.
// EPI 1: relu -> bf16.
// ============================================================================
template<int EPI>
__global__ void __launch_bounds__(512, 1)
gemm_bt8(const __hip_bfloat16* __restrict__ A, const __hip_bfloat16* __restrict__ B,
         __hip_bfloat16* __restrict__ Cb, int M, int N, int K)
{
  extern __shared__ __align__(16) char smem[];
  const int tid  = threadIdx.x;
  const int lane = tid & 63;
  const int wave = tid >> 6;
  const int wm = wave >> 2;
  const int wn = wave & 3;

  const int nwg = gridDim.x;
  const int bid = ((int)blockIdx.x % 8) * (nwg >> 3) + ((int)blockIdx.x >> 3);

  const int nbn = N >> 8;
  const int bm = (bid / nbn) << 8;
  const int bn = (bid % nbn) << 8;

  const int NT = K >> 6;

  f32x4 acc[8][4];
  const f32x4 zero = {0.f, 0.f, 0.f, 0.f};
#pragma unroll
  for (int i = 0; i < 8; ++i)
#pragma unroll
    for (int j = 0; j < 4; ++j)
      acc[i][j] = zero;

  const int cs8 = (((tid & 3) ^ ((tid >> 3) & 3)) << 3);
  const __hip_bfloat16* Ag = A + (size_t)(bm + (tid >> 2)) * K + cs8;
  const __hip_bfloat16* Bg = B + (size_t)(bn + (tid >> 2)) * K + cs8;

  const int rl = lane & 15;
  const int kc = lane >> 4;
  const int chunk_off = ((kc ^ ((rl >> 1) & 3)) << 4);
  const int aoff = ((wm << 7) + rl) * 64 + chunk_off;
  const int boff = ((wn << 6) + rl) * 64 + chunk_off;

#define STAGE_A(S, KH) do { \
    const int kt_ = (((S) & (NT - 1)) << 6) + ((KH) << 5); \
    char* dst_ = smem + (((((S) & 1) << 1) | (KH)) << 14) + (tid << 4); \
    load_lds16(Ag + kt_, dst_); \
    load_lds16(Ag + (size_t)128 * K + kt_, dst_ + 8192); \
  } while (0)

#define STAGE_B(S, KH) do { \
    const int kt_ = (((S) & (NT - 1)) << 6) + ((KH) << 5); \
    char* dst_ = smem + 65536 + (((((S) & 1) << 1) | (KH)) << 14) + (tid << 4); \
    load_lds16(Bg + kt_, dst_); \
    load_lds16(Bg + (size_t)128 * K + kt_, dst_ + 8192); \
  } while (0)

  bf16x8 afS[2][4];
  bf16x8 bf0, bf1, bf2, bf3;

#define MFMA_ROW(MI, AF) \
    acc[MI][0] = __builtin_amdgcn_mfma_f32_16x16x32_bf16(AF, bf0, acc[MI][0], 0, 0, 0); \
    acc[MI][1] = __builtin_amdgcn_mfma_f32_16x16x32_bf16(AF, bf1, acc[MI][1], 0, 0, 0); \
    acc[MI][2] = __builtin_amdgcn_mfma_f32_16x16x32_bf16(AF, bf2, acc[MI][2], 0, 0, 0); \
    acc[MI][3] = __builtin_amdgcn_mfma_f32_16x16x32_bf16(AF, bf3, acc[MI][3], 0, 0, 0);

#define PH(PN, KHN, MHN, ASETN, ACUR, MHC, DOBP, BP, BKH, STG, VM) do { \
    { const char* ab_ = smem + ((((PN) << 1) | (KHN)) << 14) + aoff + (MHN) * 4096; \
      afS[ASETN][0] = *(const bf16x8*)(ab_); \
      afS[ASETN][1] = *(const bf16x8*)(ab_ + 1024); \
      afS[ASETN][2] = *(const bf16x8*)(ab_ + 2048); \
      afS[ASETN][3] = *(const bf16x8*)(ab_ + 3072); } \
    STG; \
    if (VM) { asm volatile("s_waitcnt vmcnt(6)" ::: "memory"); } \
    asm volatile("s_barrier" ::: "memory"); \
    __builtin_amdgcn_sched_barrier(0); \
    __builtin_amdgcn_s_setprio(1); \
    MFMA_ROW((MHC) * 4 + 0, afS[ACUR][0]) \
    MFMA_ROW((MHC) * 4 + 1, afS[ACUR][1]) \
    MFMA_ROW((MHC) * 4 + 2, afS[ACUR][2]) \
    MFMA_ROW((MHC) * 4 + 3, afS[ACUR][3]) \
    __builtin_amdgcn_s_setprio(0); \
    if (DOBP) { \
      const char* bb_ = smem + 65536 + ((((BP) << 1) | (BKH)) << 14) + boff; \
      bf0 = *(const bf16x8*)(bb_); bf1 = *(const bf16x8*)(bb_ + 1024); \
      bf2 = *(const bf16x8*)(bb_ + 2048); bf3 = *(const bf16x8*)(bb_ + 3072); } \
    asm volatile("s_barrier" ::: "memory"); \
  } while (0)

  STAGE_A(0, 0); STAGE_B(0, 0);
  STAGE_A(0, 1); STAGE_B(0, 1);
  STAGE_A(1, 0); STAGE_B(1, 0);
  asm volatile("s_waitcnt vmcnt(4)" ::: "memory");
  asm volatile("s_barrier" ::: "memory");
  {
    const char* ab_ = smem + aoff;
    afS[1][0] = *(const bf16x8*)(ab_);
    afS[1][1] = *(const bf16x8*)(ab_ + 1024);
    afS[1][2] = *(const bf16x8*)(ab_ + 2048);
    afS[1][3] = *(const bf16x8*)(ab_ + 3072);
    const char* bb_ = smem + 65536 + boff;
    bf0 = *(const bf16x8*)(bb_); bf1 = *(const bf16x8*)(bb_ + 1024);
    bf2 = *(const bf16x8*)(bb_ + 2048); bf3 = *(const bf16x8*)(bb_ + 3072);
  }

#pragma unroll 1
  for (int t = 0; t < NT; t += 2) {
    PH(0, 0, 1, 0, 1, 0, 0, 0, 0, STAGE_A(t + 1, 1), 1);
    PH(0, 1, 0, 1, 0, 1, 1, 0, 1, STAGE_B(t + 1, 1), 0);
    PH(0, 1, 1, 0, 1, 0, 0, 0, 0, STAGE_A(t + 2, 0), 1);
    PH(1, 0, 0, 1, 0, 1, 1, 1, 0, STAGE_B(t + 2, 0), 0);
    PH(1, 0, 1, 0, 1, 0, 0, 0, 0, STAGE_A(t + 2, 1), 1);
    PH(1, 1, 0, 1, 0, 1, 1, 1, 1, STAGE_B(t + 2, 1), 0);
    PH(1, 1, 1, 0, 1, 0, 0, 0, 0, STAGE_A(t + 3, 0), 1);
    PH(0, 0, 0, 1, 0, 1, 1, 0, 0, STAGE_B(t + 3, 0), 0);
  }

  const int r0 = bm + (wm << 7) + (kc << 2);
  const int c0 = bn + (wn << 6) + rl;
#pragma unroll
  for (int mi = 0; mi < 8; ++mi) {
#pragma unroll
    for (int nf = 0; nf < 4; ++nf) {
#pragma unroll
      for (int q = 0; q < 4; ++q) {
        const int r = r0 + (mi << 4) + q;
        const int c = c0 + (nf << 4);
        float v = fmaxf(acc[mi][nf][q], 0.f);
        Cb[(size_t)r * N + c] = __float2bfloat16(v);
      }
    }
  }

#undef STAGE_A
#undef STAGE_B
#undef MFMA_ROW
#undef PH
}

// ============================================================================
// 256x256 8-phase INT8 GEMM — same verified schedule, K in BYTES (=elems),
// K-tile = 128 B (NT = K>>7), mfma_i32_16x16x64_i8, i32 acc, dequant epilogue
// h2 = relu(sA[r] * sB[c] * acc) -> bf16, block sum -> atomicAdd(vsum).
// Fragment mapping (assumed, mirrors bf16): lane&15=row, lane>>4=16-byte
// k-chunk, bytes consecutive in k.
// ============================================================================
__global__ void __launch_bounds__(512, 1)
gemm_i8_bt8(const uint8_t* __restrict__ A, const uint8_t* __restrict__ B,
            __hip_bfloat16* __restrict__ Cb, int M, int N, int K,
            float* __restrict__ vsum,
            const float* __restrict__ sA, const float* __restrict__ sB)
{
  extern __shared__ __align__(16) char smem[];
  const int tid  = threadIdx.x;
  const int lane = tid & 63;
  const int wave = tid >> 6;
  const int wm = wave >> 2;
  const int wn = wave & 3;

  const int nwg = gridDim.x;
  const int bid = ((int)blockIdx.x % 8) * (nwg >> 3) + ((int)blockIdx.x >> 3);

  const int nbn = N >> 8;
  const int bm = (bid / nbn) << 8;
  const int bn = (bid % nbn) << 8;

  const int NT = K >> 7;   // 128 bytes of k per tile

  i32x4 acc[8][4];
  const i32x4 izero = {0, 0, 0, 0};
#pragma unroll
  for (int i = 0; i < 8; ++i)
#pragma unroll
    for (int j = 0; j < 4; ++j)
      acc[i][j] = izero;

  // staging: thread row tid>>2 (+128 on 2nd issue), 16B chunk tid&3,
  // source pre-swizzled by (row>>1)&3 (byte offsets).
  const int csb = (((tid & 3) ^ ((tid >> 3) & 3)) << 4);
  const uint8_t* Ag = A + (size_t)(bm + (tid >> 2)) * K + csb;
  const uint8_t* Bg = B + (size_t)(bn + (tid >> 2)) * K + csb;

  const int rl = lane & 15;
  const int kc = lane >> 4;
  const int chunk_off = ((kc ^ ((rl >> 1) & 3)) << 4);
  const int aoff = ((wm << 7) + rl) * 64 + chunk_off;
  const int boff = ((wn << 6) + rl) * 64 + chunk_off;

#define STAGE_A8(S, KH) do { \
    const int kt_ = (((S) & (NT - 1)) << 7) + ((KH) << 6); \
    char* dst_ = smem + (((((S) & 1) << 1) | (KH)) << 14) + (tid << 4); \
    load_lds16(Ag + kt_, dst_); \
    load_lds16(Ag + (size_t)128 * K + kt_, dst_ + 8192); \
  } while (0)

#define STAGE_B8(S, KH) do { \
    const int kt_ = (((S) & (NT - 1)) << 7) + ((KH) << 6); \
    char* dst_ = smem + 65536 + (((((S) & 1) << 1) | (KH)) << 14) + (tid << 4); \
    load_lds16(Bg + kt_, dst_); \
    load_lds16(Bg + (size_t)128 * K + kt_, dst_ + 8192); \
  } while (0)

  i32x4 afS[2][4];
  i32x4 bf0, bf1, bf2, bf3;

#define MFMA_ROW8(MI, AF) \
    acc[MI][0] = __builtin_amdgcn_mfma_i32_16x16x64_i8(AF, bf0, acc[MI][0], 0, 0, 0); \
    acc[MI][1] = __builtin_amdgcn_mfma_i32_16x16x64_i8(AF, bf1, acc[MI][1], 0, 0, 0); \
    acc[MI][2] = __builtin_amdgcn_mfma_i32_16x16x64_i8(AF, bf2, acc[MI][2], 0, 0, 0); \
    acc[MI][3] = __builtin_amdgcn_mfma_i32_16x16x64_i8(AF, bf3, acc[MI][3], 0, 0, 0);

#define PH8(PN, KHN, MHN, ASETN, ACUR, MHC, DOBP, BP, BKH, STG, VM) do { \
    { const char* ab_ = smem + ((((PN) << 1) | (KHN)) << 14) + aoff + (MHN) * 4096; \
      afS[ASETN][0] = *(const i32x4*)(ab_); \
      afS[ASETN][1] = *(const i32x4*)(ab_ + 1024); \
      afS[ASETN][2] = *(const i32x4*)(ab_ + 2048); \
      afS[ASETN][3] = *(const i32x4*)(ab_ + 3072); } \
    STG; \
    if (VM) { asm volatile("s_waitcnt vmcnt(6)" ::: "memory"); } \
    asm volatile("s_barrier" ::: "memory"); \
    __builtin_amdgcn_sched_barrier(0); \
    __builtin_amdgcn_s_setprio(1); \
    MFMA_ROW8((MHC) * 4 + 0, afS[ACUR][0]) \
    MFMA_ROW8((MHC) * 4 + 1, afS[ACUR][1]) \
    MFMA_ROW8((MHC) * 4 + 2, afS[ACUR][2]) \
    MFMA_ROW8((MHC) * 4 + 3, afS[ACUR][3]) \
    __builtin_amdgcn_s_setprio(0); \
    if (DOBP) { \
      const char* bb_ = smem + 65536 + ((((BP) << 1) | (BKH)) << 14) + boff; \
      bf0 = *(const i32x4*)(bb_); bf1 = *(const i32x4*)(bb_ + 1024); \
      bf2 = *(const i32x4*)(bb_ + 2048); bf3 = *(const i32x4*)(bb_ + 3072); } \
    asm volatile("s_barrier" ::: "memory"); \
  } while (0)

  STAGE_A8(0, 0); STAGE_B8(0, 0);
  STAGE_A8(0, 1); STAGE_B8(0, 1);
  STAGE_A8(1, 0); STAGE_B8(1, 0);
  asm volatile("s_waitcnt vmcnt(4)" ::: "memory");
  asm volatile("s_barrier" ::: "memory");
  {
    const char* ab_ = smem + aoff;
    afS[1][0] = *(const i32x4*)(ab_);
    afS[1][1] = *(const i32x4*)(ab_ + 1024);
    afS[1][2] = *(const i32x4*)(ab_ + 2048);
    afS[1][3] = *(const i32x4*)(ab_ + 3072);
    const char* bb_ = smem + 65536 + boff;
    bf0 = *(const i32x4*)(bb_); bf1 = *(const i32x4*)(bb_ + 1024);
    bf2 = *(const i32x4*)(bb_ + 2048); bf3 = *(const i32x4*)(bb_ + 3072);
  }

#pragma unroll 1
  for (int t = 0; t < NT; t += 2) {
    PH8(0, 0, 1, 0, 1, 0, 0, 0, 0, STAGE_A8(t + 1, 1), 1);
    PH8(0, 1, 0, 1, 0, 1, 1, 0, 1, STAGE_B8(t + 1, 1), 0);
    PH8(0, 1, 1, 0, 1, 0, 0, 0, 0, STAGE_A8(t + 2, 0), 1);
    PH8(1, 0, 0, 1, 0, 1, 1, 1, 0, STAGE_B8(t + 2, 0), 0);
    PH8(1, 0, 1, 0, 1, 0, 0, 0, 0, STAGE_A8(t + 2, 1), 1);
    PH8(1, 1, 0, 1, 0, 1, 1, 1, 1, STAGE_B8(t + 2, 1), 0);
    PH8(1, 1, 1, 0, 1, 0, 0, 0, 0, STAGE_A8(t + 3, 0), 1);
    PH8(0, 0, 0, 1, 0, 1, 1, 0, 0, STAGE_B8(t + 3, 0), 0);
  }

  const int r0 = bm + (wm << 7) + (kc << 2);
  const int c0 = bn + (wn << 6) + rl;
  float lsum = 0.f;
#pragma unroll
  for (int mi = 0; mi < 8; ++mi) {
#pragma unroll
    for (int nf = 0; nf < 4; ++nf) {
#pragma unroll
      for (int q = 0; q < 4; ++q) {
        const int r = r0 + (mi << 4) + q;
        const int c = c0 + (nf << 4);
        float v = (float)acc[mi][nf][q] * sA[r] * sB[c];
        v = fmaxf(v, 0.f);
        Cb[(size_t)r * N + c] = __float2bfloat16(v);
        lsum += v;
      }
    }
  }
#pragma unroll
  for (int off = 32; off > 0; off >>= 1)
    lsum += __shfl_down(lsum, off);
  if (lane == 0) atomicAdd(vsum, lsum);

#undef STAGE_A8
#undef STAGE_B8
#undef MFMA_ROW8
#undef PH8
}

// ============================================================================
// 128x128 2-barrier INT8 GEMM (m97-clone, K in bytes, BK=128B) — pred.
// out = sA[r] * sB[c] * acc -> bf16 (no relu).
// ============================================================================
__global__ void __launch_bounds__(256)
gemm_i8_128(const uint8_t* __restrict__ A, const uint8_t* __restrict__ B,
            __hip_bfloat16* __restrict__ Cb, int M, int N, int K,
            const float* __restrict__ sA, const float* __restrict__ sB)
{
  __shared__ __align__(16) char smem[32768];
  const int tid  = threadIdx.x;
  const int lane = tid & 63;
  const int wave = tid >> 6;

  const int nbn = N >> 7;
  const int bm = ((int)blockIdx.x / nbn) << 7;
  const int bn = ((int)blockIdx.x % nbn) << 7;

  const int wm = (wave >> 1) << 6;
  const int wn = (wave & 1) << 6;

  i32x4 acc[4][4];
  const i32x4 izero = {0, 0, 0, 0};
#pragma unroll
  for (int i = 0; i < 4; ++i)
#pragma unroll
    for (int j = 0; j < 4; ++j)
      acc[i][j] = izero;

  const int srow = tid >> 3;
  const int schk = (tid & 7) ^ (srow & 7);
  const uint8_t* Ag = A + (size_t)(bm + srow) * K + (schk << 4);
  const uint8_t* Bg = B + (size_t)(bn + srow) * K + (schk << 4);
  char* ldsA = smem + (wave << 10);
  char* ldsB = smem + 16384 + (wave << 10);

  const int aoff0 = (wm + (lane & 15)) << 7;
  const int boff0 = 16384 + ((wn + (lane & 15)) << 7);
  const int kc = lane >> 4;
  const int sw = lane & 7;

  for (int k0 = 0; k0 < K; k0 += 128) {
#pragma unroll
    for (int i = 0; i < 4; ++i)
      load_lds16(Ag + (size_t)(i << 5) * K + k0, ldsA + (i << 12));
#pragma unroll
    for (int i = 0; i < 4; ++i)
      load_lds16(Bg + (size_t)(i << 5) * K + k0, ldsB + (i << 12));
    __syncthreads();
#pragma unroll
    for (int ks = 0; ks < 2; ++ks) {
      const int cb = ((kc + (ks << 2)) ^ sw) << 4;
      i32x4 af[4], bfr[4];
#pragma unroll
      for (int i = 0; i < 4; ++i)
        af[i] = *reinterpret_cast<const i32x4*>(smem + aoff0 + (i << 11) + cb);
#pragma unroll
      for (int j = 0; j < 4; ++j)
        bfr[j] = *reinterpret_cast<const i32x4*>(smem + boff0 + (j << 11) + cb);
#pragma unroll
      for (int i = 0; i < 4; ++i)
#pragma unroll
        for (int j = 0; j < 4; ++j)
          acc[i][j] = __builtin_amdgcn_mfma_i32_16x16x64_i8(af[i], bfr[j], acc[i][j], 0, 0, 0);
    }
    __syncthreads();
  }

  const int r0 = bm + wm + ((lane >> 4) << 2);
  const int c0 = bn + wn + (lane & 15);
#pragma unroll
  for (int i = 0; i < 4; ++i) {
#pragma unroll
    for (int j = 0; j < 4; ++j) {
#pragma unroll
      for (int q = 0; q < 4; ++q) {
        const int r = r0 + (i << 4) + q;
        const int c = c0 + (j << 4);
        const float v = (float)acc[i][j][q] * sA[r] * sB[c];
        Cb[(size_t)r * N + c] = __float2bfloat16(v);
      }
    }
  }
}

// ============================================================================
// 128x128 2-barrier bf16 GEMM — final gate only:
// out = x + sigmoid(v + b_gate) * pred (f32).
// ============================================================================
__global__ void __launch_bounds__(256)
gemm_gate(const __hip_bfloat16* __restrict__ A, const __hip_bfloat16* __restrict__ B,
          float* __restrict__ Cf, int M, int N, int K,
          const float* __restrict__ Xf, const __hip_bfloat16* __restrict__ PredBf,
          const float* __restrict__ Bgate)
{
  __shared__ __align__(16) char smem[32768];
  const int tid  = threadIdx.x;
  const int lane = tid & 63;
  const int wave = tid >> 6;

  const int nbn = N >> 7;
  const int bm = ((int)blockIdx.x / nbn) << 7;
  const int bn = ((int)blockIdx.x % nbn) << 7;

  const int wm = (wave >> 1) << 6;
  const int wn = (wave & 1) << 6;

  const f32x4 zero = {0.f, 0.f, 0.f, 0.f};
  f32x4 acc[4][4];
#pragma unroll
  for (int i = 0; i < 4; ++i)
#pragma unroll
    for (int j = 0; j < 4; ++j)
      acc[i][j] = zero;

  const int srow = tid >> 3;
  const int schk = (tid & 7) ^ (srow & 7);
  const __hip_bfloat16* Ag = A + (size_t)(bm + srow) * K + (schk << 3);
  const __hip_bfloat16* Bg = B + (size_t)(bn + srow) * K + (schk << 3);
  char* ldsA = smem + (wave << 10);
  char* ldsB = smem + 16384 + (wave << 10);

  const int aoff0 = (wm + (lane & 15)) << 7;
  const int boff0 = 16384 + ((wn + (lane & 15)) << 7);
  const int kc = lane >> 4;
  const int sw = lane & 7;

  for (int k0 = 0; k0 < K; k0 += 64) {
#pragma unroll
    for (int i = 0; i < 4; ++i)
      load_lds16(Ag + (size_t)(i << 5) * K + k0, ldsA + (i << 12));
#pragma unroll
    for (int i = 0; i < 4; ++i)
      load_lds16(Bg + (size_t)(i << 5) * K + k0, ldsB + (i << 12));
    __syncthreads();
#pragma unroll
    for (int ks = 0; ks < 2; ++ks) {
      const int cb = ((kc + (ks << 2)) ^ sw) << 4;
      bf16x8 af[4], bfr[4];
#pragma unroll
      for (int i = 0; i < 4; ++i)
        af[i] = *reinterpret_cast<const bf16x8*>(smem + aoff0 + (i << 11) + cb);
#pragma unroll
      for (int j = 0; j < 4; ++j)
        bfr[j] = *reinterpret_cast<const bf16x8*>(smem + boff0 + (j << 11) + cb);
#pragma unroll
      for (int i = 0; i < 4; ++i)
#pragma unroll
        for (int j = 0; j < 4; ++j)
          acc[i][j] = __builtin_amdgcn_mfma_f32_16x16x32_bf16(af[i], bfr[j], acc[i][j], 0, 0, 0);
    }
    __syncthreads();
  }

  const int r0 = bm + wm + ((lane >> 4) << 2);
  const int c0 = bn + wn + (lane & 15);
#pragma unroll
  for (int i = 0; i < 4; ++i) {
#pragma unroll
    for (int j = 0; j < 4; ++j) {
#pragma unroll
      for (int q = 0; q < 4; ++q) {
        const int r = r0 + (i << 4) + q;
        const int c = c0 + (j << 4);
        const size_t idx = (size_t)r * N + c;
        const float g = 1.f / (1.f + __expf(-(acc[i][j][q] + Bgate[c])));
        Cf[idx] = Xf[idx] + g * __bfloat162float(PredBf[idx]);
      }
    }
  }
}

// ============================================================================
// kwta, wave-per-row, register-resident, no LDS/atomics/barriers.
// Exact threshold via 16-step binary search on u16 bf16 keys (nonneg).
// Emits INT8 quantized normalized row + per-row scale:
//   q = rint(v/vmax*127) for kept v (else 0); sA = vmax*inv/127
// so q*sA == v*inv (the normalized value).
// MODE 0: always write.  MODE 1: only when *vsumPtr >= EPS (else keep old).
// ============================================================================
template<int MODE>
__global__ void __launch_bounds__(256)
kwta_wave(const __hip_bfloat16* __restrict__ H, uint8_t* __restrict__ OUTQ,
          float* __restrict__ sA, const float* __restrict__ vsumPtr,
          const int* __restrict__ kptr)
{
  const int tid  = threadIdx.x;
  const int lane = tid & 63;
  const int w    = tid >> 6;
  const int row  = ((int)blockIdx.x << 2) + w;

  if constexpr (MODE == 1) {
    if (!(*vsumPtr >= 1e-10f)) return;
  }

  const uint4* h8 = (const uint4*)(H + (size_t)row * 4096);
  uint4 d[8];
#pragma unroll
  for (int i = 0; i < 8; ++i) d[i] = h8[(i << 6) + lane];

  const unsigned k = (unsigned)(*kptr);

  // row max key
  unsigned kmax = 0;
#pragma unroll
  for (int i = 0; i < 8; ++i) {
    const unsigned* p = (const unsigned*)&d[i];
#pragma unroll
    for (int c4 = 0; c4 < 4; ++c4) {
      kmax = max(kmax, p[c4] & 0xffffu);
      kmax = max(kmax, p[c4] >> 16);
    }
  }
#pragma unroll
  for (int off = 32; off > 0; off >>= 1) kmax = max(kmax, __shfl_xor(kmax, off));

  // binary search: largest T with count(key >= T) >= k
  unsigned lo = 0, hi = 65536;
#pragma unroll 1
  for (int it = 0; it < 16; ++it) {
    const unsigned mid = (lo + hi) >> 1;
    unsigned c = 0;
#pragma unroll
    for (int i = 0; i < 8; ++i) {
      const unsigned* p = (const unsigned*)&d[i];
#pragma unroll
      for (int c4 = 0; c4 < 4; ++c4) {
        c += ((p[c4] & 0xffffu) >= mid) ? 1u : 0u;
        c += ((p[c4] >> 16) >= mid) ? 1u : 0u;
      }
    }
#pragma unroll
    for (int off = 32; off > 0; off >>= 1) c += __shfl_xor(c, off);
    if (c >= k) lo = mid; else hi = mid;
  }
  const unsigned threshKey = lo;

  // sum of squares over kept values
  float ss = 0.f;
#pragma unroll
  for (int i = 0; i < 8; ++i) {
    const unsigned* p = (const unsigned*)&d[i];
#pragma unroll
    for (int c4 = 0; c4 < 4; ++c4) {
#pragma unroll
      for (int hh = 0; hh < 2; ++hh) {
        const unsigned key = hh ? (p[c4] >> 16) : (p[c4] & 0xffffu);
        if (key >= threshKey) {
          const float v = __uint_as_float(key << 16);
          ss = fmaf(v, v, ss);
        }
      }
    }
  }
#pragma unroll
  for (int off = 32; off > 0; off >>= 1) ss += __shfl_xor(ss, off);
  const float inv = 1.f / fmaxf(sqrtf(ss), 1e-10f);

  const float vmaxf = __uint_as_float(kmax << 16);
  const float r127 = (kmax > 0) ? 127.f / vmaxf : 0.f;

  if (lane == 0) sA[row] = vmaxf * inv * (1.f / 127.f);

  // quantize + pack: 8 i8 per d[i], stored as uint2 at matching offset
  uint2* o2 = (uint2*)(OUTQ + (size_t)row * 4096);
#pragma unroll
  for (int i = 0; i < 8; ++i) {
    const unsigned* p = (const unsigned*)&d[i];
    unsigned b[8];
#pragma unroll
    for (int c4 = 0; c4 < 4; ++c4) {
#pragma unroll
      for (int hh = 0; hh < 2; ++hh) {
        const unsigned key = hh ? (p[c4] >> 16) : (p[c4] & 0xffffu);
        unsigned q = 0;
        if (key >= threshKey && key > 0) {
          const float v = __uint_as_float(key << 16);
          q = (unsigned)__float2int_rn(v * r127) & 0xffu;
        }
        b[c4 * 2 + hh] = q;
      }
    }
    uint2 o;
    o.x = b[0] | (b[1] << 8) | (b[2] << 16) | (b[3] << 24);
    o.y = b[4] | (b[5] << 8) | (b[6] << 16) | (b[7] << 24);
    o2[(i << 6) + lane] = o;
  }
}

// ============================================================================
// Per-row weight quantization, wave-per-row (K=4096 f32 in registers):
// rows 0..4095 -> W_ca3 / qc / sc ; rows 4096..5119 -> W_up / qu / su.
// s = absmax/127 ; q = rint(w/s) in int8.
// ============================================================================
__global__ void __launch_bounds__(256)
quant_rows(const float* __restrict__ Wc, const float* __restrict__ Wu,
           uint8_t* __restrict__ qc, uint8_t* __restrict__ qu,
           float* __restrict__ sc, float* __restrict__ su)
{
  const int wgl = ((int)blockIdx.x << 2) + (threadIdx.x >> 6);
  const int lane = threadIdx.x & 63;

  const float* W; uint8_t* q; float* s; int row;
  if (wgl < 4096) { W = Wc; q = qc; s = sc; row = wgl; }
  else            { W = Wu; q = qu; s = su; row = wgl - 4096; }

  const float4* src = (const float4*)(W + (size_t)row * 4096);
  float4 v[16];
  float am = 0.f;
#pragma unroll
  for (int i = 0; i < 16; ++i) {
    v[i] = src[(i << 6) + lane];
    am = fmaxf(am, fmaxf(fmaxf(fabsf(v[i].x), fabsf(v[i].y)),
                         fmaxf(fabsf(v[i].z), fabsf(v[i].w))));
  }
#pragma unroll
  for (int off = 32; off > 0; off >>= 1) am = fmaxf(am, __shfl_xor(am, off));

  const float rinv = (am > 0.f) ? 127.f / am : 0.f;
  unsigned* qo = (unsigned*)(q + (size_t)row * 4096);
#pragma unroll
  for (int i = 0; i < 16; ++i) {
    const unsigned b0 = (unsigned)__float2int_rn(v[i].x * rinv) & 0xffu;
    const unsigned b1 = (unsigned)__float2int_rn(v[i].y * rinv) & 0xffu;
    const unsigned b2 = (unsigned)__float2int_rn(v[i].z * rinv) & 0xffu;
    const unsigned b3 = (unsigned)__float2int_rn(v[i].w * rinv) & 0xffu;
    qo[(i << 6) + lane] = b0 | (b1 << 8) | (b2 << 16) | (b3 << 24);
  }
  if (lane == 0) s[row] = am * (1.f / 127.f);
}

// Fused f32 -> bf16 conversion: x, W_down, W_gate (8 elems / thread).
__global__ void __launch_bounds__(256)
cvt_all(const float* __restrict__ x,  const float* __restrict__ wd,
        const float* __restrict__ wg,
        __hip_bfloat16* __restrict__ xo,  __hip_bfloat16* __restrict__ wdo,
        __hip_bfloat16* __restrict__ wgo)
{
  const int i = blockIdx.x * 256 + threadIdx.x;
  const int C0 = 1048576, C1 = 1572864, C2 = 1703936;
  const float* in; __hip_bfloat16* out; int off;
  if      (i < C0) { in = x;  out = xo;  off = i; }
  else if (i < C1) { in = wd; out = wdo; off = i - C0; }
  else if (i < C2) { in = wg; out = wgo; off = i - C1; }
  else return;
  const float4 a = ((const float4*)in)[2 * off];
  const float4 b = ((const float4*)in)[2 * off + 1];
  unsigned r0 = (f32_to_bf16_rne(a.y) << 16) | f32_to_bf16_rne(a.x);
  unsigned r1 = (f32_to_bf16_rne(a.w) << 16) | f32_to_bf16_rne(a.z);
  unsigned r2 = (f32_to_bf16_rne(b.y) << 16) | f32_to_bf16_rne(b.x);
  unsigned r3 = (f32_to_bf16_rne(b.w) << 16) | f32_to_bf16_rne(b.z);
  ((uint4*)out)[off] = make_uint4(r0, r1, r2, r3);
}

__global__ void diag_kernel(float* out, float mb)
{
  if (threadIdx.x == 0 && blockIdx.x == 0) out[0] = -mb;
}

extern "C" void kernel_launch(void* const* d_in, const int* in_sizes, int n_in,
                              void* d_out, int out_size, void* d_ws, size_t ws_size,
                              hipStream_t stream)
{
  const float* x     = (const float*)d_in[0]; // (8192,1024)
  const float* Wdown = (const float*)d_in[1]; // (4096,1024)
  const float* Wup   = (const float*)d_in[2]; // (1024,4096)
  const float* Wgate = (const float*)d_in[3]; // (1024,1024)
  const float* bgate = (const float*)d_in[4]; // (1024,)
  const float* Wca3  = (const float*)d_in[5]; // (4096,4096)
  const int*   kptr  = (const int*)d_in[6];

  const size_t OFF_XBF  = 0;          // 16 MB bf16 x
  const size_t OFF_WDBF = 16777216;   //  8 MB bf16 W_down
  const size_t OFF_WGBF = 25165824;   //  2 MB bf16 W_gate
  const size_t OFF_WCQ  = 27262976;   // 16 MB i8 W_ca3
  const size_t OFF_WUQ  = 44040192;   //  4 MB i8 W_up
  const size_t OFF_SWC  = 48234496;   // 16 KB f32 W_ca3 row scales
  const size_t OFF_SWU  = 48250880;   //  4 KB f32 W_up row scales
  const size_t OFF_SA   = 48254976;   // 32 KB f32 sparse row scales
  const size_t OFF_VSUM = 48287744;   // 4 B (padded to 4 KB)
  const size_t OFF_SPQ  = 48291840;   // 32 MB i8 sparse/successor
  const size_t OFF_H    = 81846272;   // 64 MB bf16 h1/h2; pred (16 MB bf16) aliases
  const size_t NEED     = 148955136;

  if (ws_size < NEED) {
    diag_kernel<<<1, 64, 0, stream>>>((float*)d_out, (float)(ws_size >> 20));
    return;
  }

  char* ws = (char*)d_ws;
  __hip_bfloat16* xbf  = (__hip_bfloat16*)(ws + OFF_XBF);
  __hip_bfloat16* wdbf = (__hip_bfloat16*)(ws + OFF_WDBF);
  __hip_bfloat16* wgbf = (__hip_bfloat16*)(ws + OFF_WGBF);
  uint8_t*        wcq  = (uint8_t*)       (ws + OFF_WCQ);
  uint8_t*        wuq  = (uint8_t*)       (ws + OFF_WUQ);
  float*          swc  = (float*)         (ws + OFF_SWC);
  float*          swu  = (float*)         (ws + OFF_SWU);
  float*          sA   = (float*)         (ws + OFF_SA);
  float*          vsum = (float*)         (ws + OFF_VSUM);
  uint8_t*        spq  = (uint8_t*)       (ws + OFF_SPQ);
  __hip_bfloat16* h    = (__hip_bfloat16*)(ws + OFF_H);
  __hip_bfloat16* pred = (__hip_bfloat16*)(ws + OFF_H);   // aliases h (dead by then)

  hipMemsetAsync(vsum, 0, sizeof(float), stream);

  // f32 -> bf16 (x, W_down, W_gate): 1703936 items
  cvt_all<<<6656, 256, 0, stream>>>(x, Wdown, Wgate, xbf, wdbf, wgbf);
  // W_ca3 + W_up -> int8 with per-row scales (5120 rows, wave per row)
  quant_rows<<<1280, 256, 0, stream>>>(Wca3, Wup, wcq, wuq, swc, swu);

  // h1 = relu(x @ W_down.T) -> bf16   [256^2 8-phase bf16, grid 512]
  gemm_bt8<1><<<(MROWS >> 8) * (DN >> 8), 512, 131072, stream>>>(
      xbf, wdbf, h, MROWS, DN, DD);
  // sparse = kwta(h1)/norm -> i8 + scale
  kwta_wave<0><<<MROWS / 4, 256, 0, stream>>>(h, spq, sA, nullptr, kptr);
  // h2 = relu(sA*sW * (spq @ wcq^T)) -> bf16, sum -> vsum   [i8 8-phase]
  gemm_i8_bt8<<<(MROWS >> 8) * (DN >> 8), 512, 131072, stream>>>(
      spq, wcq, h, MROWS, DN, DN, vsum, sA, swc);
  // successor = valid ? kwta(h2)/norm : sparse (i8 + scale, in-place)
  kwta_wave<1><<<MROWS / 4, 256, 0, stream>>>(h, spq, sA, vsum, kptr);
  // pred = successor @ W_up.T -> bf16   [i8 128^2, grid 512]
  gemm_i8_128<<<(MROWS >> 7) * (DD >> 7), 256, 0, stream>>>(
      spq, wuq, pred, MROWS, DD, DN, sA, swu);
  // out = x + sigmoid(x @ W_gate.T + b_gate) * pred   [bf16 128^2]
  gemm_gate<<<(MROWS >> 7) * (DD >> 7), 256, 0, stream>>>(
      xbf, wgbf, (float*)d_out, MROWS, DD, DD, x, pred, bgate);
}